// Round 19
// baseline (250.726 us; speedup 1.0000x reference)
//
#include <hip/hip_runtime.h>
#include <stdint.h>

// ---- problem constants ----
#define Tn   2048
#define Cn   1024
#define NHn  16
#define Hn   64
#define FFn  3072
#define Mrows 4096           // B*T
#define LNEPS 1e-6f

#if __has_builtin(__builtin_amdgcn_exp2f)
#define EXP2(x) __builtin_amdgcn_exp2f(x)
#else
#define EXP2(x) exp2f(x)
#endif

typedef float f32x4 __attribute__((ext_vector_type(4)));
typedef __bf16 bf16x8 __attribute__((ext_vector_type(8)));
typedef unsigned short us8 __attribute__((ext_vector_type(8)));
typedef unsigned short us4 __attribute__((ext_vector_type(4)));
typedef unsigned int u32x4 __attribute__((ext_vector_type(4)));
typedef unsigned int u32x2 __attribute__((ext_vector_type(2)));

__device__ __forceinline__ unsigned short f2bf(float f) {
    return __builtin_bit_cast(unsigned short, (__bf16)f);
}

__device__ __forceinline__ uint32_t pk2bf(float lo, float hi) {
    return (uint32_t)f2bf(lo) | ((uint32_t)f2bf(hi) << 16);
}

__device__ __forceinline__ void gl_lds16(const void* g, void* l) {
    __builtin_amdgcn_global_load_lds(
        (const __attribute__((address_space(1))) void*)g,
        (__attribute__((address_space(3))) void*)l, 16, 0, 0);
}

// ---------------- weight prep (all four casts fused into one launch) ----------------
#define CQ  (3072 * 1024)
#define CWO (1024 * 1024)
#define CW1 (3072 * 1024)
__global__ __launch_bounds__(256) void cast_all_kernel(
    const float* __restrict__ Wq, const float* __restrict__ Wk,
    const float* __restrict__ Wv, const float* __restrict__ Wo,
    const float* __restrict__ W1, const float* __restrict__ W2,
    unsigned short* __restrict__ wqkv, unsigned short* __restrict__ wo,
    unsigned short* __restrict__ w1,   unsigned short* __restrict__ w2)
{
    int idx = blockIdx.x * 256 + threadIdx.x;
    if (idx < CQ) {
        int n = idx >> 10, cc = idx & 1023;
        const float* W = (n < 1024) ? Wq : ((n < 2048) ? Wk : Wv);
        int nn = n & 1023;
        wqkv[idx] = f2bf(W[(size_t)((nn >> 6) * 1024 + cc) * 64 + (nn & 63)]);
    } else if (idx < CQ + CWO) {
        int j = idx - CQ;
        wo[j] = f2bf(Wo[j]);
    } else if (idx < CQ + CWO + CW1) {
        int j = idx - CQ - CWO;
        w1[j] = f2bf(W1[j]);
    } else {
        int j = idx - CQ - CWO - CW1;
        w2[j] = f2bf(W2[j]);
    }
}

// ---------------- layernorm (torch: ddof=1, eps on std) ----------------
__global__ __launch_bounds__(256) void ln_kernel(
    const float* __restrict__ xin, const float* __restrict__ gamma,
    const float* __restrict__ beta, unsigned short* __restrict__ out)
{
    const int row = blockIdx.x;
    const int tid = threadIdx.x;
    const float4 v = ((const float4*)(xin + (size_t)row * Cn))[tid];
    float s  = v.x + v.y + v.z + v.w;
    float ss = v.x*v.x + v.y*v.y + v.z*v.z + v.w*v.w;
    #pragma unroll
    for (int off = 1; off < 64; off <<= 1) {
        s  += __shfl_xor(s, off);
        ss += __shfl_xor(ss, off);
    }
    __shared__ float red[8];
    const int wave = tid >> 6, lane = tid & 63;
    if (lane == 0) { red[wave] = s; red[4 + wave] = ss; }
    __syncthreads();
    float S  = red[0] + red[1] + red[2] + red[3];
    float SS = red[4] + red[5] + red[6] + red[7];
    float mean = S * (1.0f / 1024.0f);
    float var  = (SS - 1024.0f * mean * mean) * (1.0f / 1023.0f);
    var = fmaxf(var, 0.0f);
    float inv = 1.0f / (sqrtf(var) + LNEPS);
    const float4 gv = ((const float4*)gamma)[tid];
    const float4 bv = ((const float4*)beta)[tid];
    us4 ov;
    ov[0] = f2bf(gv.x * (v.x - mean) * inv + bv.x);
    ov[1] = f2bf(gv.y * (v.y - mean) * inv + bv.y);
    ov[2] = f2bf(gv.z * (v.z - mean) * inv + bv.z);
    ov[3] = f2bf(gv.w * (v.w - mean) * inv + bv.w);
    *(us4*)(out + (size_t)row * Cn + tid * 4) = ov;
}

// ---------------- GEMM 128x128 (all four GEMMs): R14 proven ----------------
template<int MODE>
__global__ __launch_bounds__(512) void gemm_bt(
    const unsigned short* __restrict__ A,
    const unsigned short* __restrict__ Bt,
    void* Cout,                      // may alias resid (FF2) -> no restrict
    const float* __restrict__ bias,
    const float* resid,
    int M, int N, int K)
{
    __shared__ unsigned short lds[3][8192];   // per buf: A[128][32] @0, B[128][32] @4096
    const int tid  = threadIdx.x;
    const int wave = tid >> 6, lane = tid & 63;
    const int g = lane >> 4, c = lane & 15;
    const int wr = wave >> 2, wc = wave & 3;
    const int m0 = blockIdx.x * 128, n0 = blockIdx.y * 128;

    f32x4 acc[4][2];
    #pragma unroll
    for (int i = 0; i < 4; i++)
        #pragma unroll
        for (int j = 0; j < 2; j++) acc[i][j] = (f32x4){0.f, 0.f, 0.f, 0.f};

    const int srow = wave * 16 + (lane >> 2);
    const int scol = (((lane & 3) ^ ((lane >> 3) & 3)) * 8);
    const unsigned short* sA = A  + (size_t)(m0 + srow) * K + scol;
    const unsigned short* sB = Bt + (size_t)(n0 + srow) * K + scol;
    const int wdst = wave * 512;

    auto STAGE = [&](int t, int b) {
        const int ko = t * 32;
        gl_lds16(sA + ko, &lds[b][wdst]);
        gl_lds16(sB + ko, &lds[b][4096 + wdst]);
    };

    STAGE(0, 0);
    STAGE(1, 1);
    asm volatile("s_waitcnt vmcnt(2)" ::: "memory");
    __builtin_amdgcn_s_barrier();

    const int jsw = (g ^ ((c >> 1) & 3)) * 8;

    const int NT = K >> 5;
    int cur = 0;
    for (int t = 0; t < NT; ++t) {
        const bool pf = (t + 2 < NT);
        if (pf) { int b = cur + 2; if (b >= 3) b -= 3; STAGE(t + 2, b); }

        bf16x8 af[4], bfr[2];
        #pragma unroll
        for (int mi = 0; mi < 4; mi++)
            af[mi]  = *(const bf16x8*)&lds[cur][(wr * 64 + mi * 16 + c) * 32 + jsw];
        #pragma unroll
        for (int ni = 0; ni < 2; ni++)
            bfr[ni] = *(const bf16x8*)&lds[cur][4096 + (wc * 32 + ni * 16 + c) * 32 + jsw];
        __builtin_amdgcn_s_setprio(1);
        #pragma unroll
        for (int mi = 0; mi < 4; mi++)
            #pragma unroll
            for (int ni = 0; ni < 2; ni++)
                acc[mi][ni] = __builtin_amdgcn_mfma_f32_16x16x32_bf16(
                    af[mi], bfr[ni], acc[mi][ni], 0, 0, 0);
        __builtin_amdgcn_s_setprio(0);

        if (pf) asm volatile("s_waitcnt vmcnt(2)" ::: "memory");
        else    asm volatile("s_waitcnt vmcnt(0)" ::: "memory");
        __builtin_amdgcn_s_barrier();
        cur = (cur == 2) ? 0 : cur + 1;
    }

    const int rowb = m0 + wr * 64 + g * 4;
    const int colb = n0 + wc * 32 + c;
    #pragma unroll
    for (int mi = 0; mi < 4; mi++) {
        #pragma unroll
        for (int ni = 0; ni < 2; ni++) {
            const int col = colb + ni * 16;
            float bv = (MODE == 1 || MODE == 2) ? bias[col] : 0.f;
            #pragma unroll
            for (int r = 0; r < 4; r++) {
                const int row = rowb + mi * 16 + r;
                float v = acc[mi][ni][r];
                if (MODE == 1) {
                    float res = resid[(size_t)row * N + col];
                    ((float*)Cout)[(size_t)row * N + col] = v + bv + res;
                } else if (MODE == 2) {
                    float t = v + bv;
                    t = t > 0.f ? t : 0.f;
                    ((unsigned short*)Cout)[(size_t)row * N + col] = f2bf(t);
                } else {
                    ((unsigned short*)Cout)[(size_t)row * N + col] = f2bf(v);
                }
            }
        }
    }
}

// ---------------- V transpose: qkv v-part [b][t][h*64+d] -> vt[bh][d][t] ----------------
__global__ __launch_bounds__(256) void transpose_v_kernel(
    const unsigned short* __restrict__ qkv, unsigned short* __restrict__ vt)
{
    __shared__ unsigned short tile[64][72];
    const int bh = blockIdx.y;
    const int b = bh >> 4, h = bh & 15;
    const int t0 = blockIdx.x * 64;
    const int tid = threadIdx.x;
    const int tr = tid >> 2;
    const int dc = (tid & 3) * 16;
    const unsigned short* src =
        qkv + (size_t)(b * Tn + t0 + tr) * 3072 + 2048 + h * 64 + dc;
    *(us8*)&tile[tr][dc]     = *(const us8*)src;
    *(us8*)&tile[tr][dc + 8] = *(const us8*)(src + 8);
    __syncthreads();
    const int dr = tid >> 2;
    const int tc = (tid & 3) * 16;
    unsigned short* dst = vt + (size_t)bh * Hn * Tn + (size_t)dr * Tn + t0 + tc;
    us8 o0, o1;
    #pragma unroll
    for (int e = 0; e < 8; e++) o0[e] = tile[tc + e][dr];
    #pragma unroll
    for (int e = 0; e < 8; e++) o1[e] = tile[tc + 8 + e][dr];
    *(us8*)dst       = o0;
    *(us8*)(dst + 8) = o1;
}

// ---------------- flash attention: 1 block per q-tile, 2-wave split-K ----------------
// Grid 2048 = 8 blocks/CU (2x TLP vs R18).  LPT: tileIdx = 63 - (l>>5) so 32-chunk
// blocks dispatch first; scheduler backfills short blocks.  XCD decode on l&31 keeps
// each bh's 64 blocks on one XCD.  Body/merge identical to R18.
__global__ __launch_bounds__(128, 4) void attn_kernel(
    const unsigned short* __restrict__ qkv,
    const unsigned short* __restrict__ vt,
    unsigned short* __restrict__ ctx)
{
    const float SCL = 0.125f * 1.44269504088896f;
    __shared__ float Osh[2][4][64][4];
    __shared__ float Msh[2][64];
    __shared__ float Lsh[2][64];
    __shared__ uint32_t Psh[2][2][16][36];

    const int tid  = threadIdx.x;
    const int wave = tid >> 6, lane = tid & 63;
    const int g = lane >> 4, c = lane & 15;
    const int l = blockIdx.x;                         // 0..2047
    const int tileIdx = 63 - (l >> 5);                // LPT: big tiles first
    const int bh = ((l & 7) << 2) | ((l >> 3) & 3);   // XCD-locality decode
    const int b = bh >> 4, h = bh & 15;
    const unsigned short* base  = qkv + (size_t)b * Tn * 3072;
    const unsigned short* qbase = base + h * 64;
    const unsigned short* kbase = base + 1024 + h * 64;
    const unsigned short* vtb   = vt + (size_t)bh * (Hn * Tn);

    const int t0 = tileIdx * 32;
    const int nch  = (t0 + 95) >> 6;        // chunks of 64 covering s < t0+32
    const int nh0  = (nch + 1) >> 1;
    const int cbeg = wave ? nh0 : 0;
    const int cend = wave ? nch : nh0;

    bf16x8 qf[2][2];
    #pragma unroll
    for (int qa = 0; qa < 2; qa++) {
        const unsigned short* qp = qbase + (size_t)(t0 + qa * 16 + c) * 3072 + g * 8;
        qf[qa][0] = *(const bf16x8*)qp;
        qf[qa][1] = *(const bf16x8*)(qp + 32);
    }

    float mrun[2] = {-1e30f, -1e30f};
    float lrun[2] = {0.f, 0.f};
    f32x4 o[2][4];
    #pragma unroll
    for (int qa = 0; qa < 2; qa++)
        #pragma unroll
        for (int nc = 0; nc < 4; nc++) o[qa][nc] = (f32x4){0.f, 0.f, 0.f, 0.f};

    for (int ci = cbeg; ci < cend; ++ci) {
        const int s0 = ci * 64;
        bf16x8 kf[4][2];
        #pragma unroll
        for (int sc = 0; sc < 4; sc++) {
            const unsigned short* kp = kbase + (size_t)(s0 + sc * 16 + c) * 3072 + g * 8;
            kf[sc][0] = *(const bf16x8*)kp;
            kf[sc][1] = *(const bf16x8*)(kp + 32);
        }
        bf16x8 vf[4][2];
        #pragma unroll
        for (int nc = 0; nc < 4; nc++)
            #pragma unroll
            for (int ks = 0; ks < 2; ks++)
                vf[nc][ks] = *(const bf16x8*)(vtb + (size_t)(nc * 16 + c) * Tn
                                              + s0 + ks * 32 + g * 8);

        f32x4 sacc[2][4];
        #pragma unroll
        for (int qa = 0; qa < 2; qa++)
            #pragma unroll
            for (int sc = 0; sc < 4; sc++) {
                f32x4 z = (f32x4){0.f, 0.f, 0.f, 0.f};
                z = __builtin_amdgcn_mfma_f32_16x16x32_bf16(kf[sc][0], qf[qa][0], z, 0, 0, 0);
                z = __builtin_amdgcn_mfma_f32_16x16x32_bf16(kf[sc][1], qf[qa][1], z, 0, 0, 0);
                sacc[qa][sc] = z;
            }

        uint32_t dw[2][4][2];
        #pragma unroll
        for (int qa = 0; qa < 2; qa++) {
            const int q = t0 + qa * 16 + c;
            float pm[4][4];
            const bool needMask = (s0 + 63 > t0 + qa * 16);
            #pragma unroll
            for (int sc = 0; sc < 4; sc++)
                #pragma unroll
                for (int r = 0; r < 4; r++) {
                    float v = sacc[qa][sc][r] * SCL;
                    if (needMask && (s0 + sc * 16 + 4 * g + r > q)) v = -1e30f;
                    pm[sc][r] = v;
                }
            float tmax = pm[0][0];
            #pragma unroll
            for (int sc = 0; sc < 4; sc++)
                #pragma unroll
                for (int r = 0; r < 4; r++) tmax = fmaxf(tmax, pm[sc][r]);
            tmax = fmaxf(tmax, __shfl_xor(tmax, 16));
            tmax = fmaxf(tmax, __shfl_xor(tmax, 32));
            float mnew = fmaxf(mrun[qa], tmax);
            float corr = EXP2(mrun[qa] - mnew);
            mrun[qa] = mnew;
            float csum = 0.f;
            #pragma unroll
            for (int sc = 0; sc < 4; sc++)
                #pragma unroll
                for (int r = 0; r < 4; r++) {
                    float p = EXP2(pm[sc][r] - mnew);
                    pm[sc][r] = p;
                    csum += p;
                }
            csum += __shfl_xor(csum, 16);
            csum += __shfl_xor(csum, 32);
            lrun[qa] = lrun[qa] * corr + csum;
            float cb[4];
            #pragma unroll
            for (int r = 0; r < 4; r++) cb[r] = __shfl(corr, 4 * g + r);
            #pragma unroll
            for (int nc = 0; nc < 4; nc++)
                #pragma unroll
                for (int r = 0; r < 4; r++) o[qa][nc][r] *= cb[r];
            #pragma unroll
            for (int sc = 0; sc < 4; sc++) {
                dw[qa][sc][0] = pk2bf(pm[sc][0], pm[sc][1]);
                dw[qa][sc][1] = pk2bf(pm[sc][2], pm[sc][3]);
            }
        }

        #pragma unroll
        for (int qa = 0; qa < 2; qa++)
            #pragma unroll
            for (int sc = 0; sc < 4; sc++) {
                u32x2 wv = { dw[qa][sc][0], dw[qa][sc][1] };
                *(u32x2*)&Psh[wave][qa][c][sc * 8 + 2 * g] = wv;
            }
        #pragma unroll
        for (int ks = 0; ks < 2; ks++) {
            #pragma unroll
            for (int qa = 0; qa < 2; qa++) {
                u32x4 pd = *(const u32x4*)&Psh[wave][qa][c][ks * 16 + 4 * g];
                bf16x8 pa = __builtin_bit_cast(bf16x8, pd);
                #pragma unroll
                for (int nc = 0; nc < 4; nc++)
                    o[qa][nc] = __builtin_amdgcn_mfma_f32_16x16x32_bf16(
                        pa, vf[nc][ks], o[qa][nc], 0, 0, 0);
            }
        }
    }

    // ---- split-K merge (rule-#20 safe: static indices under uniform branch) ----
    f32x4 oS[4], oX[4];
    float mS, lS, mX, lX;
    if (wave == 0) {
        #pragma unroll
        for (int nc = 0; nc < 4; nc++) { oS[nc] = o[0][nc]; oX[nc] = o[1][nc]; }
        mS = mrun[0]; lS = lrun[0]; mX = mrun[1]; lX = lrun[1];
    } else {
        #pragma unroll
        for (int nc = 0; nc < 4; nc++) { oS[nc] = o[1][nc]; oX[nc] = o[0][nc]; }
        mS = mrun[1]; lS = lrun[1]; mX = mrun[0]; lX = lrun[0];
    }
    #pragma unroll
    for (int nc = 0; nc < 4; nc++)
        *(f32x4*)&Osh[wave][nc][lane][0] = oX[nc];
    Msh[wave][lane] = mX;
    Lsh[wave][lane] = lX;
    __syncthreads();
    const int pw = wave ^ 1;
    float mP = Msh[pw][lane];
    float lP = Lsh[pw][lane];
    float mM = fmaxf(mS, mP);
    float cS = EXP2(mS - mM);
    float cP = EXP2(mP - mM);
    float rl = 1.0f / (lS * cS + lP * cP);
    float cbS[4], cbP[4], lb[4];
    #pragma unroll
    for (int r = 0; r < 4; r++) {
        cbS[r] = __shfl(cS, 4 * g + r);
        cbP[r] = __shfl(cP, 4 * g + r);
        lb[r]  = __shfl(rl, 4 * g + r);
    }
    #pragma unroll
    for (int nc = 0; nc < 4; nc++) {
        f32x4 oP = *(const f32x4*)&Osh[pw][nc][lane][0];
        #pragma unroll
        for (int r = 0; r < 4; r++) {
            const int trow = t0 + wave * 16 + 4 * g + r;
            float val = (oS[nc][r] * cbS[r] + oP[r] * cbP[r]) * lb[r];
            ctx[(size_t)(b * Tn + trow) * 1024 + h * 64 + nc * 16 + c] = f2bf(val);
        }
    }
}

// ---------------- launch ----------------
extern "C" void kernel_launch(void* const* d_in, const int* in_sizes, int n_in,
                              void* d_out, int out_size, void* d_ws, size_t ws_size,
                              hipStream_t stream) {
    const float* x   = (const float*)d_in[0];
    const float* Wq  = (const float*)d_in[1];
    const float* Wk  = (const float*)d_in[2];
    const float* Wv  = (const float*)d_in[3];
    const float* Wo  = (const float*)d_in[4];
    const float* bo  = (const float*)d_in[5];
    const float* W1  = (const float*)d_in[6];
    const float* b1  = (const float*)d_in[7];
    const float* W2  = (const float*)d_in[8];
    const float* b2  = (const float*)d_in[9];
    const float* g1  = (const float*)d_in[10];
    const float* be1 = (const float*)d_in[11];
    const float* g2  = (const float*)d_in[12];
    const float* be2 = (const float*)d_in[13];

    char* ws = (char*)d_ws;
    unsigned short* wqkv = (unsigned short*)ws;  ws += (size_t)3072 * 1024 * 2;
    unsigned short* wo   = (unsigned short*)ws;  ws += (size_t)1024 * 1024 * 2;
    unsigned short* w1   = (unsigned short*)ws;  ws += (size_t)3072 * 1024 * 2;
    unsigned short* w2   = (unsigned short*)ws;  ws += (size_t)1024 * 3072 * 2;
    unsigned short* bufA = (unsigned short*)ws;  ws += (size_t)Mrows * 1024 * 2; // xn1 / ctx / h2
    unsigned short* bufB = (unsigned short*)ws;  ws += (size_t)Mrows * 3072 * 2; // qkv / ffh

    float* xout = (float*)d_out;           // x1 lives here after out-proj
    unsigned short* vt = (unsigned short*)d_out;   // V^T parks in dead d_out

    // weight prep (single fused launch)
    cast_all_kernel<<<40960, 256, 0, stream>>>(Wq, Wk, Wv, Wo, W1, W2,
                                               wqkv, wo, w1, w2);

    // xn1 = LN(x)
    ln_kernel<<<Mrows, 256, 0, stream>>>(x, g1, be1, bufA);
    // qkv = xn1 @ Wqkv^T
    gemm_bt<0><<<dim3(32, 24), 512, 0, stream>>>(bufA, wqkv, bufB, nullptr, nullptr,
                                                 Mrows, 3072, 1024);
    // vt = V^T
    transpose_v_kernel<<<dim3(Tn / 64, 2 * NHn), 256, 0, stream>>>(bufB, vt);
    // ctx = attention(qkv, vt)  — 1 block/q-tile, 8 blocks/CU, LPT + XCD decode
    attn_kernel<<<dim3(2048), 128, 0, stream>>>(bufB, vt, bufA);
    // x1 = x + ctx @ Wo^T + bo   (f32, into d_out; vt dead afterwards)
    gemm_bt<1><<<dim3(32, 8), 512, 0, stream>>>(bufA, wo, xout, bo, x,
                                                Mrows, 1024, 1024);
    // h2 = LN(x1)
    ln_kernel<<<Mrows, 256, 0, stream>>>(xout, g2, be2, bufA);
    // ffh = relu(h2 @ W1^T + b1)
    gemm_bt<2><<<dim3(32, 24), 512, 0, stream>>>(bufA, w1, bufB, b1, nullptr,
                                                 Mrows, 3072, 1024);
    // out = x1 + ffh @ W2^T + b2  (in-place residual from d_out)
    gemm_bt<1><<<dim3(32, 8), 512, 0, stream>>>(bufB, w2, xout, b2, (const float*)xout,
                                                Mrows, 1024, 3072);
}

// Round 20
// 235.991 us; speedup vs baseline: 1.0624x; 1.0624x over previous
//
#include <hip/hip_runtime.h>
#include <stdint.h>

// ---- problem constants ----
#define Tn   2048
#define Cn   1024
#define NHn  16
#define Hn   64
#define FFn  3072
#define Mrows 4096           // B*T
#define LNEPS 1e-6f

#if __has_builtin(__builtin_amdgcn_exp2f)
#define EXP2(x) __builtin_amdgcn_exp2f(x)
#else
#define EXP2(x) exp2f(x)
#endif

typedef float f32x4 __attribute__((ext_vector_type(4)));
typedef __bf16 bf16x8 __attribute__((ext_vector_type(8)));
typedef unsigned short us8 __attribute__((ext_vector_type(8)));
typedef unsigned short us4 __attribute__((ext_vector_type(4)));
typedef unsigned int u32x4 __attribute__((ext_vector_type(4)));
typedef unsigned int u32x2 __attribute__((ext_vector_type(2)));

__device__ __forceinline__ unsigned short f2bf(float f) {
    return __builtin_bit_cast(unsigned short, (__bf16)f);
}

__device__ __forceinline__ uint32_t pk2bf(float lo, float hi) {
    return (uint32_t)f2bf(lo) | ((uint32_t)f2bf(hi) << 16);
}

__device__ __forceinline__ void gl_lds16(const void* g, void* l) {
    __builtin_amdgcn_global_load_lds(
        (const __attribute__((address_space(1))) void*)g,
        (__attribute__((address_space(3))) void*)l, 16, 0, 0);
}

// ---------------- weight prep (all four casts fused into one launch) ----------------
#define CQ  (3072 * 1024)
#define CWO (1024 * 1024)
#define CW1 (3072 * 1024)
__global__ __launch_bounds__(256) void cast_all_kernel(
    const float* __restrict__ Wq, const float* __restrict__ Wk,
    const float* __restrict__ Wv, const float* __restrict__ Wo,
    const float* __restrict__ W1, const float* __restrict__ W2,
    unsigned short* __restrict__ wqkv, unsigned short* __restrict__ wo,
    unsigned short* __restrict__ w1,   unsigned short* __restrict__ w2)
{
    int idx = blockIdx.x * 256 + threadIdx.x;
    if (idx < CQ) {
        int n = idx >> 10, cc = idx & 1023;
        const float* W = (n < 1024) ? Wq : ((n < 2048) ? Wk : Wv);
        int nn = n & 1023;
        wqkv[idx] = f2bf(W[(size_t)((nn >> 6) * 1024 + cc) * 64 + (nn & 63)]);
    } else if (idx < CQ + CWO) {
        int j = idx - CQ;
        wo[j] = f2bf(Wo[j]);
    } else if (idx < CQ + CWO + CW1) {
        int j = idx - CQ - CWO;
        w1[j] = f2bf(W1[j]);
    } else {
        int j = idx - CQ - CWO - CW1;
        w2[j] = f2bf(W2[j]);
    }
}

// ---------------- layernorm (torch: ddof=1, eps on std) ----------------
__global__ __launch_bounds__(256) void ln_kernel(
    const float* __restrict__ xin, const float* __restrict__ gamma,
    const float* __restrict__ beta, unsigned short* __restrict__ out)
{
    const int row = blockIdx.x;
    const int tid = threadIdx.x;
    const float4 v = ((const float4*)(xin + (size_t)row * Cn))[tid];
    float s  = v.x + v.y + v.z + v.w;
    float ss = v.x*v.x + v.y*v.y + v.z*v.z + v.w*v.w;
    #pragma unroll
    for (int off = 1; off < 64; off <<= 1) {
        s  += __shfl_xor(s, off);
        ss += __shfl_xor(ss, off);
    }
    __shared__ float red[8];
    const int wave = tid >> 6, lane = tid & 63;
    if (lane == 0) { red[wave] = s; red[4 + wave] = ss; }
    __syncthreads();
    float S  = red[0] + red[1] + red[2] + red[3];
    float SS = red[4] + red[5] + red[6] + red[7];
    float mean = S * (1.0f / 1024.0f);
    float var  = (SS - 1024.0f * mean * mean) * (1.0f / 1023.0f);
    var = fmaxf(var, 0.0f);
    float inv = 1.0f / (sqrtf(var) + LNEPS);
    const float4 gv = ((const float4*)gamma)[tid];
    const float4 bv = ((const float4*)beta)[tid];
    us4 ov;
    ov[0] = f2bf(gv.x * (v.x - mean) * inv + bv.x);
    ov[1] = f2bf(gv.y * (v.y - mean) * inv + bv.y);
    ov[2] = f2bf(gv.z * (v.z - mean) * inv + bv.z);
    ov[3] = f2bf(gv.w * (v.w - mean) * inv + bv.w);
    *(us4*)(out + (size_t)row * Cn + tid * 4) = ov;
}

// ---------------- GEMM 128x128 (all four GEMMs): R14 proven ----------------
template<int MODE>
__global__ __launch_bounds__(512) void gemm_bt(
    const unsigned short* __restrict__ A,
    const unsigned short* __restrict__ Bt,
    void* Cout,                      // may alias resid (FF2) -> no restrict
    const float* __restrict__ bias,
    const float* resid,
    int M, int N, int K)
{
    __shared__ unsigned short lds[3][8192];   // per buf: A[128][32] @0, B[128][32] @4096
    const int tid  = threadIdx.x;
    const int wave = tid >> 6, lane = tid & 63;
    const int g = lane >> 4, c = lane & 15;
    const int wr = wave >> 2, wc = wave & 3;
    const int m0 = blockIdx.x * 128, n0 = blockIdx.y * 128;

    f32x4 acc[4][2];
    #pragma unroll
    for (int i = 0; i < 4; i++)
        #pragma unroll
        for (int j = 0; j < 2; j++) acc[i][j] = (f32x4){0.f, 0.f, 0.f, 0.f};

    const int srow = wave * 16 + (lane >> 2);
    const int scol = (((lane & 3) ^ ((lane >> 3) & 3)) * 8);
    const unsigned short* sA = A  + (size_t)(m0 + srow) * K + scol;
    const unsigned short* sB = Bt + (size_t)(n0 + srow) * K + scol;
    const int wdst = wave * 512;

    auto STAGE = [&](int t, int b) {
        const int ko = t * 32;
        gl_lds16(sA + ko, &lds[b][wdst]);
        gl_lds16(sB + ko, &lds[b][4096 + wdst]);
    };

    STAGE(0, 0);
    STAGE(1, 1);
    asm volatile("s_waitcnt vmcnt(2)" ::: "memory");
    __builtin_amdgcn_s_barrier();

    const int jsw = (g ^ ((c >> 1) & 3)) * 8;

    const int NT = K >> 5;
    int cur = 0;
    for (int t = 0; t < NT; ++t) {
        const bool pf = (t + 2 < NT);
        if (pf) { int b = cur + 2; if (b >= 3) b -= 3; STAGE(t + 2, b); }

        bf16x8 af[4], bfr[2];
        #pragma unroll
        for (int mi = 0; mi < 4; mi++)
            af[mi]  = *(const bf16x8*)&lds[cur][(wr * 64 + mi * 16 + c) * 32 + jsw];
        #pragma unroll
        for (int ni = 0; ni < 2; ni++)
            bfr[ni] = *(const bf16x8*)&lds[cur][4096 + (wc * 32 + ni * 16 + c) * 32 + jsw];
        __builtin_amdgcn_s_setprio(1);
        #pragma unroll
        for (int mi = 0; mi < 4; mi++)
            #pragma unroll
            for (int ni = 0; ni < 2; ni++)
                acc[mi][ni] = __builtin_amdgcn_mfma_f32_16x16x32_bf16(
                    af[mi], bfr[ni], acc[mi][ni], 0, 0, 0);
        __builtin_amdgcn_s_setprio(0);

        if (pf) asm volatile("s_waitcnt vmcnt(2)" ::: "memory");
        else    asm volatile("s_waitcnt vmcnt(0)" ::: "memory");
        __builtin_amdgcn_s_barrier();
        cur = (cur == 2) ? 0 : cur + 1;
    }

    const int rowb = m0 + wr * 64 + g * 4;
    const int colb = n0 + wc * 32 + c;
    #pragma unroll
    for (int mi = 0; mi < 4; mi++) {
        #pragma unroll
        for (int ni = 0; ni < 2; ni++) {
            const int col = colb + ni * 16;
            float bv = (MODE == 1 || MODE == 2) ? bias[col] : 0.f;
            #pragma unroll
            for (int r = 0; r < 4; r++) {
                const int row = rowb + mi * 16 + r;
                float v = acc[mi][ni][r];
                if (MODE == 1) {
                    float res = resid[(size_t)row * N + col];
                    ((float*)Cout)[(size_t)row * N + col] = v + bv + res;
                } else if (MODE == 2) {
                    float t = v + bv;
                    t = t > 0.f ? t : 0.f;
                    ((unsigned short*)Cout)[(size_t)row * N + col] = f2bf(t);
                } else {
                    ((unsigned short*)Cout)[(size_t)row * N + col] = f2bf(v);
                }
            }
        }
    }
}

// ---------------- V transpose: qkv v-part [b][t][h*64+d] -> vt[bh][d][t] ----------------
__global__ __launch_bounds__(256) void transpose_v_kernel(
    const unsigned short* __restrict__ qkv, unsigned short* __restrict__ vt)
{
    __shared__ unsigned short tile[64][72];
    const int bh = blockIdx.y;
    const int b = bh >> 4, h = bh & 15;
    const int t0 = blockIdx.x * 64;
    const int tid = threadIdx.x;
    const int tr = tid >> 2;
    const int dc = (tid & 3) * 16;
    const unsigned short* src =
        qkv + (size_t)(b * Tn + t0 + tr) * 3072 + 2048 + h * 64 + dc;
    *(us8*)&tile[tr][dc]     = *(const us8*)src;
    *(us8*)&tile[tr][dc + 8] = *(const us8*)(src + 8);
    __syncthreads();
    const int dr = tid >> 2;
    const int tc = (tid & 3) * 16;
    unsigned short* dst = vt + (size_t)bh * Hn * Tn + (size_t)dr * Tn + t0 + tc;
    us8 o0, o1;
    #pragma unroll
    for (int e = 0; e < 8; e++) o0[e] = tile[tc + e][dr];
    #pragma unroll
    for (int e = 0; e < 8; e++) o1[e] = tile[tc + 8 + e][dr];
    *(us8*)dst       = o0;
    *(us8*)(dst + 8) = o1;
}

// ---------------- flash attention: 1 block per q-tile, 2-wave split-K ----------------
// Grid 2048 = 8 blocks/CU.  NO min-wave hint (R19's (128,4) forced VGPR 64 -> spills,
// WRITE_SIZE 8->21 MB).  Natural VGPR 76 allows 6 waves/SIMD; LDS 18.4KB x 8 = 147KB OK.
// LPT: tileIdx = 63 - (l>>5); XCD decode on l&31.  Body/merge identical to R18.
__global__ __launch_bounds__(128, 2) void attn_kernel(
    const unsigned short* __restrict__ qkv,
    const unsigned short* __restrict__ vt,
    unsigned short* __restrict__ ctx)
{
    const float SCL = 0.125f * 1.44269504088896f;
    __shared__ float Osh[2][4][64][4];
    __shared__ float Msh[2][64];
    __shared__ float Lsh[2][64];
    __shared__ uint32_t Psh[2][2][16][36];

    const int tid  = threadIdx.x;
    const int wave = tid >> 6, lane = tid & 63;
    const int g = lane >> 4, c = lane & 15;
    const int l = blockIdx.x;                         // 0..2047
    const int tileIdx = 63 - (l >> 5);                // LPT: big tiles first
    const int bh = ((l & 7) << 2) | ((l >> 3) & 3);   // XCD-locality decode
    const int b = bh >> 4, h = bh & 15;
    const unsigned short* base  = qkv + (size_t)b * Tn * 3072;
    const unsigned short* qbase = base + h * 64;
    const unsigned short* kbase = base + 1024 + h * 64;
    const unsigned short* vtb   = vt + (size_t)bh * (Hn * Tn);

    const int t0 = tileIdx * 32;
    const int nch  = (t0 + 95) >> 6;        // chunks of 64 covering s < t0+32
    const int nh0  = (nch + 1) >> 1;
    const int cbeg = wave ? nh0 : 0;
    const int cend = wave ? nch : nh0;

    bf16x8 qf[2][2];
    #pragma unroll
    for (int qa = 0; qa < 2; qa++) {
        const unsigned short* qp = qbase + (size_t)(t0 + qa * 16 + c) * 3072 + g * 8;
        qf[qa][0] = *(const bf16x8*)qp;
        qf[qa][1] = *(const bf16x8*)(qp + 32);
    }

    float mrun[2] = {-1e30f, -1e30f};
    float lrun[2] = {0.f, 0.f};
    f32x4 o[2][4];
    #pragma unroll
    for (int qa = 0; qa < 2; qa++)
        #pragma unroll
        for (int nc = 0; nc < 4; nc++) o[qa][nc] = (f32x4){0.f, 0.f, 0.f, 0.f};

    for (int ci = cbeg; ci < cend; ++ci) {
        const int s0 = ci * 64;
        bf16x8 kf[4][2];
        #pragma unroll
        for (int sc = 0; sc < 4; sc++) {
            const unsigned short* kp = kbase + (size_t)(s0 + sc * 16 + c) * 3072 + g * 8;
            kf[sc][0] = *(const bf16x8*)kp;
            kf[sc][1] = *(const bf16x8*)(kp + 32);
        }
        bf16x8 vf[4][2];
        #pragma unroll
        for (int nc = 0; nc < 4; nc++)
            #pragma unroll
            for (int ks = 0; ks < 2; ks++)
                vf[nc][ks] = *(const bf16x8*)(vtb + (size_t)(nc * 16 + c) * Tn
                                              + s0 + ks * 32 + g * 8);

        f32x4 sacc[2][4];
        #pragma unroll
        for (int qa = 0; qa < 2; qa++)
            #pragma unroll
            for (int sc = 0; sc < 4; sc++) {
                f32x4 z = (f32x4){0.f, 0.f, 0.f, 0.f};
                z = __builtin_amdgcn_mfma_f32_16x16x32_bf16(kf[sc][0], qf[qa][0], z, 0, 0, 0);
                z = __builtin_amdgcn_mfma_f32_16x16x32_bf16(kf[sc][1], qf[qa][1], z, 0, 0, 0);
                sacc[qa][sc] = z;
            }

        uint32_t dw[2][4][2];
        #pragma unroll
        for (int qa = 0; qa < 2; qa++) {
            const int q = t0 + qa * 16 + c;
            float pm[4][4];
            const bool needMask = (s0 + 63 > t0 + qa * 16);
            #pragma unroll
            for (int sc = 0; sc < 4; sc++)
                #pragma unroll
                for (int r = 0; r < 4; r++) {
                    float v = sacc[qa][sc][r] * SCL;
                    if (needMask && (s0 + sc * 16 + 4 * g + r > q)) v = -1e30f;
                    pm[sc][r] = v;
                }
            float tmax = pm[0][0];
            #pragma unroll
            for (int sc = 0; sc < 4; sc++)
                #pragma unroll
                for (int r = 0; r < 4; r++) tmax = fmaxf(tmax, pm[sc][r]);
            tmax = fmaxf(tmax, __shfl_xor(tmax, 16));
            tmax = fmaxf(tmax, __shfl_xor(tmax, 32));
            float mnew = fmaxf(mrun[qa], tmax);
            float corr = EXP2(mrun[qa] - mnew);
            mrun[qa] = mnew;
            float csum = 0.f;
            #pragma unroll
            for (int sc = 0; sc < 4; sc++)
                #pragma unroll
                for (int r = 0; r < 4; r++) {
                    float p = EXP2(pm[sc][r] - mnew);
                    pm[sc][r] = p;
                    csum += p;
                }
            csum += __shfl_xor(csum, 16);
            csum += __shfl_xor(csum, 32);
            lrun[qa] = lrun[qa] * corr + csum;
            float cb[4];
            #pragma unroll
            for (int r = 0; r < 4; r++) cb[r] = __shfl(corr, 4 * g + r);
            #pragma unroll
            for (int nc = 0; nc < 4; nc++)
                #pragma unroll
                for (int r = 0; r < 4; r++) o[qa][nc][r] *= cb[r];
            #pragma unroll
            for (int sc = 0; sc < 4; sc++) {
                dw[qa][sc][0] = pk2bf(pm[sc][0], pm[sc][1]);
                dw[qa][sc][1] = pk2bf(pm[sc][2], pm[sc][3]);
            }
        }

        #pragma unroll
        for (int qa = 0; qa < 2; qa++)
            #pragma unroll
            for (int sc = 0; sc < 4; sc++) {
                u32x2 wv = { dw[qa][sc][0], dw[qa][sc][1] };
                *(u32x2*)&Psh[wave][qa][c][sc * 8 + 2 * g] = wv;
            }
        #pragma unroll
        for (int ks = 0; ks < 2; ks++) {
            #pragma unroll
            for (int qa = 0; qa < 2; qa++) {
                u32x4 pd = *(const u32x4*)&Psh[wave][qa][c][ks * 16 + 4 * g];
                bf16x8 pa = __builtin_bit_cast(bf16x8, pd);
                #pragma unroll
                for (int nc = 0; nc < 4; nc++)
                    o[qa][nc] = __builtin_amdgcn_mfma_f32_16x16x32_bf16(
                        pa, vf[nc][ks], o[qa][nc], 0, 0, 0);
            }
        }
    }

    // ---- split-K merge (rule-#20 safe: static indices under uniform branch) ----
    f32x4 oS[4], oX[4];
    float mS, lS, mX, lX;
    if (wave == 0) {
        #pragma unroll
        for (int nc = 0; nc < 4; nc++) { oS[nc] = o[0][nc]; oX[nc] = o[1][nc]; }
        mS = mrun[0]; lS = lrun[0]; mX = mrun[1]; lX = lrun[1];
    } else {
        #pragma unroll
        for (int nc = 0; nc < 4; nc++) { oS[nc] = o[1][nc]; oX[nc] = o[0][nc]; }
        mS = mrun[1]; lS = lrun[1]; mX = mrun[0]; lX = lrun[0];
    }
    #pragma unroll
    for (int nc = 0; nc < 4; nc++)
        *(f32x4*)&Osh[wave][nc][lane][0] = oX[nc];
    Msh[wave][lane] = mX;
    Lsh[wave][lane] = lX;
    __syncthreads();
    const int pw = wave ^ 1;
    float mP = Msh[pw][lane];
    float lP = Lsh[pw][lane];
    float mM = fmaxf(mS, mP);
    float cS = EXP2(mS - mM);
    float cP = EXP2(mP - mM);
    float rl = 1.0f / (lS * cS + lP * cP);
    float cbS[4], cbP[4], lb[4];
    #pragma unroll
    for (int r = 0; r < 4; r++) {
        cbS[r] = __shfl(cS, 4 * g + r);
        cbP[r] = __shfl(cP, 4 * g + r);
        lb[r]  = __shfl(rl, 4 * g + r);
    }
    #pragma unroll
    for (int nc = 0; nc < 4; nc++) {
        f32x4 oP = *(const f32x4*)&Osh[pw][nc][lane][0];
        #pragma unroll
        for (int r = 0; r < 4; r++) {
            const int trow = t0 + wave * 16 + 4 * g + r;
            float val = (oS[nc][r] * cbS[r] + oP[r] * cbP[r]) * lb[r];
            ctx[(size_t)(b * Tn + trow) * 1024 + h * 64 + nc * 16 + c] = f2bf(val);
        }
    }
}

// ---------------- launch ----------------
extern "C" void kernel_launch(void* const* d_in, const int* in_sizes, int n_in,
                              void* d_out, int out_size, void* d_ws, size_t ws_size,
                              hipStream_t stream) {
    const float* x   = (const float*)d_in[0];
    const float* Wq  = (const float*)d_in[1];
    const float* Wk  = (const float*)d_in[2];
    const float* Wv  = (const float*)d_in[3];
    const float* Wo  = (const float*)d_in[4];
    const float* bo  = (const float*)d_in[5];
    const float* W1  = (const float*)d_in[6];
    const float* b1  = (const float*)d_in[7];
    const float* W2  = (const float*)d_in[8];
    const float* b2  = (const float*)d_in[9];
    const float* g1  = (const float*)d_in[10];
    const float* be1 = (const float*)d_in[11];
    const float* g2  = (const float*)d_in[12];
    const float* be2 = (const float*)d_in[13];

    char* ws = (char*)d_ws;
    unsigned short* wqkv = (unsigned short*)ws;  ws += (size_t)3072 * 1024 * 2;
    unsigned short* wo   = (unsigned short*)ws;  ws += (size_t)1024 * 1024 * 2;
    unsigned short* w1   = (unsigned short*)ws;  ws += (size_t)3072 * 1024 * 2;
    unsigned short* w2   = (unsigned short*)ws;  ws += (size_t)1024 * 3072 * 2;
    unsigned short* bufA = (unsigned short*)ws;  ws += (size_t)Mrows * 1024 * 2; // xn1 / ctx / h2
    unsigned short* bufB = (unsigned short*)ws;  ws += (size_t)Mrows * 3072 * 2; // qkv / ffh

    float* xout = (float*)d_out;           // x1 lives here after out-proj
    unsigned short* vt = (unsigned short*)d_out;   // V^T parks in dead d_out

    // weight prep (single fused launch)
    cast_all_kernel<<<40960, 256, 0, stream>>>(Wq, Wk, Wv, Wo, W1, W2,
                                               wqkv, wo, w1, w2);

    // xn1 = LN(x)
    ln_kernel<<<Mrows, 256, 0, stream>>>(x, g1, be1, bufA);
    // qkv = xn1 @ Wqkv^T
    gemm_bt<0><<<dim3(32, 24), 512, 0, stream>>>(bufA, wqkv, bufB, nullptr, nullptr,
                                                 Mrows, 3072, 1024);
    // vt = V^T
    transpose_v_kernel<<<dim3(Tn / 64, 2 * NHn), 256, 0, stream>>>(bufB, vt);
    // ctx = attention(qkv, vt)  — 1 block/q-tile, 8 blocks/CU, no VGPR cap
    attn_kernel<<<dim3(2048), 128, 0, stream>>>(bufB, vt, bufA);
    // x1 = x + ctx @ Wo^T + bo   (f32, into d_out; vt dead afterwards)
    gemm_bt<1><<<dim3(32, 8), 512, 0, stream>>>(bufA, wo, xout, bo, x,
                                                Mrows, 1024, 1024);
    // h2 = LN(x1)
    ln_kernel<<<Mrows, 256, 0, stream>>>(xout, g2, be2, bufA);
    // ffh = relu(h2 @ W1^T + b1)
    gemm_bt<2><<<dim3(32, 24), 512, 0, stream>>>(bufA, w1, bufB, b1, nullptr,
                                                 Mrows, 3072, 1024);
    // out = x1 + ffh @ W2^T + b2  (in-place residual from d_out)
    gemm_bt<1><<<dim3(32, 8), 512, 0, stream>>>(bufB, w2, xout, b2, (const float*)xout,
                                                Mrows, 1024, 3072);
}

// Round 21
// 233.991 us; speedup vs baseline: 1.0715x; 1.0085x over previous
//
#include <hip/hip_runtime.h>
#include <stdint.h>

// ---- problem constants ----
#define Tn   2048
#define Cn   1024
#define NHn  16
#define Hn   64
#define FFn  3072
#define Mrows 4096           // B*T
#define LNEPS 1e-6f

#if __has_builtin(__builtin_amdgcn_exp2f)
#define EXP2(x) __builtin_amdgcn_exp2f(x)
#else
#define EXP2(x) exp2f(x)
#endif

typedef float f32x4 __attribute__((ext_vector_type(4)));
typedef __bf16 bf16x8 __attribute__((ext_vector_type(8)));
typedef unsigned short us8 __attribute__((ext_vector_type(8)));
typedef unsigned short us4 __attribute__((ext_vector_type(4)));
typedef unsigned int u32x4 __attribute__((ext_vector_type(4)));
typedef unsigned int u32x2 __attribute__((ext_vector_type(2)));

__device__ __forceinline__ unsigned short f2bf(float f) {
    return __builtin_bit_cast(unsigned short, (__bf16)f);
}

__device__ __forceinline__ uint32_t pk2bf(float lo, float hi) {
    return (uint32_t)f2bf(lo) | ((uint32_t)f2bf(hi) << 16);
}

__device__ __forceinline__ void gl_lds16(const void* g, void* l) {
    __builtin_amdgcn_global_load_lds(
        (const __attribute__((address_space(1))) void*)g,
        (__attribute__((address_space(3))) void*)l, 16, 0, 0);
}

// ---------------- weight prep (all four casts fused into one launch) ----------------
#define CQ  (3072 * 1024)
#define CWO (1024 * 1024)
#define CW1 (3072 * 1024)
__global__ __launch_bounds__(256) void cast_all_kernel(
    const float* __restrict__ Wq, const float* __restrict__ Wk,
    const float* __restrict__ Wv, const float* __restrict__ Wo,
    const float* __restrict__ W1, const float* __restrict__ W2,
    unsigned short* __restrict__ wqkv, unsigned short* __restrict__ wo,
    unsigned short* __restrict__ w1,   unsigned short* __restrict__ w2)
{
    int idx = blockIdx.x * 256 + threadIdx.x;
    if (idx < CQ) {
        int n = idx >> 10, cc = idx & 1023;
        const float* W = (n < 1024) ? Wq : ((n < 2048) ? Wk : Wv);
        int nn = n & 1023;
        wqkv[idx] = f2bf(W[(size_t)((nn >> 6) * 1024 + cc) * 64 + (nn & 63)]);
    } else if (idx < CQ + CWO) {
        int j = idx - CQ;
        wo[j] = f2bf(Wo[j]);
    } else if (idx < CQ + CWO + CW1) {
        int j = idx - CQ - CWO;
        w1[j] = f2bf(W1[j]);
    } else {
        int j = idx - CQ - CWO - CW1;
        w2[j] = f2bf(W2[j]);
    }
}

// ---------------- layernorm (torch: ddof=1, eps on std) ----------------
__global__ __launch_bounds__(256) void ln_kernel(
    const float* __restrict__ xin, const float* __restrict__ gamma,
    const float* __restrict__ beta, unsigned short* __restrict__ out)
{
    const int row = blockIdx.x;
    const int tid = threadIdx.x;
    const float4 v = ((const float4*)(xin + (size_t)row * Cn))[tid];
    float s  = v.x + v.y + v.z + v.w;
    float ss = v.x*v.x + v.y*v.y + v.z*v.z + v.w*v.w;
    #pragma unroll
    for (int off = 1; off < 64; off <<= 1) {
        s  += __shfl_xor(s, off);
        ss += __shfl_xor(ss, off);
    }
    __shared__ float red[8];
    const int wave = tid >> 6, lane = tid & 63;
    if (lane == 0) { red[wave] = s; red[4 + wave] = ss; }
    __syncthreads();
    float S  = red[0] + red[1] + red[2] + red[3];
    float SS = red[4] + red[5] + red[6] + red[7];
    float mean = S * (1.0f / 1024.0f);
    float var  = (SS - 1024.0f * mean * mean) * (1.0f / 1023.0f);
    var = fmaxf(var, 0.0f);
    float inv = 1.0f / (sqrtf(var) + LNEPS);
    const float4 gv = ((const float4*)gamma)[tid];
    const float4 bv = ((const float4*)beta)[tid];
    us4 ov;
    ov[0] = f2bf(gv.x * (v.x - mean) * inv + bv.x);
    ov[1] = f2bf(gv.y * (v.y - mean) * inv + bv.y);
    ov[2] = f2bf(gv.z * (v.z - mean) * inv + bv.z);
    ov[3] = f2bf(gv.w * (v.w - mean) * inv + bv.w);
    *(us4*)(out + (size_t)row * Cn + tid * 4) = ov;
}

// ---------------- GEMM 128x128 (all four GEMMs): R14 proven ----------------
template<int MODE>
__global__ __launch_bounds__(512) void gemm_bt(
    const unsigned short* __restrict__ A,
    const unsigned short* __restrict__ Bt,
    void* Cout,                      // may alias resid (FF2) -> no restrict
    const float* __restrict__ bias,
    const float* resid,
    int M, int N, int K)
{
    __shared__ unsigned short lds[3][8192];   // per buf: A[128][32] @0, B[128][32] @4096
    const int tid  = threadIdx.x;
    const int wave = tid >> 6, lane = tid & 63;
    const int g = lane >> 4, c = lane & 15;
    const int wr = wave >> 2, wc = wave & 3;
    const int m0 = blockIdx.x * 128, n0 = blockIdx.y * 128;

    f32x4 acc[4][2];
    #pragma unroll
    for (int i = 0; i < 4; i++)
        #pragma unroll
        for (int j = 0; j < 2; j++) acc[i][j] = (f32x4){0.f, 0.f, 0.f, 0.f};

    const int srow = wave * 16 + (lane >> 2);
    const int scol = (((lane & 3) ^ ((lane >> 3) & 3)) * 8);
    const unsigned short* sA = A  + (size_t)(m0 + srow) * K + scol;
    const unsigned short* sB = Bt + (size_t)(n0 + srow) * K + scol;
    const int wdst = wave * 512;

    auto STAGE = [&](int t, int b) {
        const int ko = t * 32;
        gl_lds16(sA + ko, &lds[b][wdst]);
        gl_lds16(sB + ko, &lds[b][4096 + wdst]);
    };

    STAGE(0, 0);
    STAGE(1, 1);
    asm volatile("s_waitcnt vmcnt(2)" ::: "memory");
    __builtin_amdgcn_s_barrier();

    const int jsw = (g ^ ((c >> 1) & 3)) * 8;

    const int NT = K >> 5;
    int cur = 0;
    for (int t = 0; t < NT; ++t) {
        const bool pf = (t + 2 < NT);
        if (pf) { int b = cur + 2; if (b >= 3) b -= 3; STAGE(t + 2, b); }

        bf16x8 af[4], bfr[2];
        #pragma unroll
        for (int mi = 0; mi < 4; mi++)
            af[mi]  = *(const bf16x8*)&lds[cur][(wr * 64 + mi * 16 + c) * 32 + jsw];
        #pragma unroll
        for (int ni = 0; ni < 2; ni++)
            bfr[ni] = *(const bf16x8*)&lds[cur][4096 + (wc * 32 + ni * 16 + c) * 32 + jsw];
        __builtin_amdgcn_s_setprio(1);
        #pragma unroll
        for (int mi = 0; mi < 4; mi++)
            #pragma unroll
            for (int ni = 0; ni < 2; ni++)
                acc[mi][ni] = __builtin_amdgcn_mfma_f32_16x16x32_bf16(
                    af[mi], bfr[ni], acc[mi][ni], 0, 0, 0);
        __builtin_amdgcn_s_setprio(0);

        if (pf) asm volatile("s_waitcnt vmcnt(2)" ::: "memory");
        else    asm volatile("s_waitcnt vmcnt(0)" ::: "memory");
        __builtin_amdgcn_s_barrier();
        cur = (cur == 2) ? 0 : cur + 1;
    }

    const int rowb = m0 + wr * 64 + g * 4;
    const int colb = n0 + wc * 32 + c;
    #pragma unroll
    for (int mi = 0; mi < 4; mi++) {
        #pragma unroll
        for (int ni = 0; ni < 2; ni++) {
            const int col = colb + ni * 16;
            float bv = (MODE == 1 || MODE == 2) ? bias[col] : 0.f;
            #pragma unroll
            for (int r = 0; r < 4; r++) {
                const int row = rowb + mi * 16 + r;
                float v = acc[mi][ni][r];
                if (MODE == 1) {
                    float res = resid[(size_t)row * N + col];
                    ((float*)Cout)[(size_t)row * N + col] = v + bv + res;
                } else if (MODE == 2) {
                    float t = v + bv;
                    t = t > 0.f ? t : 0.f;
                    ((unsigned short*)Cout)[(size_t)row * N + col] = f2bf(t);
                } else {
                    ((unsigned short*)Cout)[(size_t)row * N + col] = f2bf(v);
                }
            }
        }
    }
}

// ---------------- V transpose: qkv v-part [b][t][h*64+d] -> vt[bh][d][t] ----------------
__global__ __launch_bounds__(256) void transpose_v_kernel(
    const unsigned short* __restrict__ qkv, unsigned short* __restrict__ vt)
{
    __shared__ unsigned short tile[64][72];
    const int bh = blockIdx.y;
    const int b = bh >> 4, h = bh & 15;
    const int t0 = blockIdx.x * 64;
    const int tid = threadIdx.x;
    const int tr = tid >> 2;
    const int dc = (tid & 3) * 16;
    const unsigned short* src =
        qkv + (size_t)(b * Tn + t0 + tr) * 3072 + 2048 + h * 64 + dc;
    *(us8*)&tile[tr][dc]     = *(const us8*)src;
    *(us8*)&tile[tr][dc + 8] = *(const us8*)(src + 8);
    __syncthreads();
    const int dr = tid >> 2;
    const int tc = (tid & 3) * 16;
    unsigned short* dst = vt + (size_t)bh * Hn * Tn + (size_t)dr * Tn + t0 + tc;
    us8 o0, o1;
    #pragma unroll
    for (int e = 0; e < 8; e++) o0[e] = tile[tc + e][dr];
    #pragma unroll
    for (int e = 0; e < 8; e++) o1[e] = tile[tc + 8 + e][dr];
    *(us8*)dst       = o0;
    *(us8*)(dst + 8) = o1;
}

// ---------------- flash attention (R18 proven best: pair-map split-K) ----------------
__global__ __launch_bounds__(128, 2) void attn_kernel(
    const unsigned short* __restrict__ qkv,
    const unsigned short* __restrict__ vt,
    unsigned short* __restrict__ ctx)
{
    const float SCL = 0.125f * 1.44269504088896f;
    __shared__ float Osh[2][4][64][4];
    __shared__ float Msh[2][64];
    __shared__ float Lsh[2][64];
    __shared__ uint32_t Psh[2][2][16][36];

    const int tid  = threadIdx.x;
    const int wave = tid >> 6, lane = tid & 63;
    const int g = lane >> 4, c = lane & 15;
    const int l = blockIdx.x;
    const int pj = l >> 5;
    const int bh = ((l & 7) << 2) | ((l >> 3) & 3);
    const int b = bh >> 4, h = bh & 15;
    const unsigned short* base  = qkv + (size_t)b * Tn * 3072;
    const unsigned short* qbase = base + h * 64;
    const unsigned short* kbase = base + 1024 + h * 64;
    const unsigned short* vtb   = vt + (size_t)bh * (Hn * Tn);

    for (int half = 0; half < 2; ++half) {
        const int tileIdx = half ? (63 - pj) : pj;
        const int t0 = tileIdx * 32;
        const int nch  = (t0 + 95) >> 6;
        const int nh0  = (nch + 1) >> 1;
        const int cbeg = wave ? nh0 : 0;
        const int cend = wave ? nch : nh0;

        bf16x8 qf[2][2];
        #pragma unroll
        for (int qa = 0; qa < 2; qa++) {
            const unsigned short* qp = qbase + (size_t)(t0 + qa * 16 + c) * 3072 + g * 8;
            qf[qa][0] = *(const bf16x8*)qp;
            qf[qa][1] = *(const bf16x8*)(qp + 32);
        }

        float mrun[2] = {-1e30f, -1e30f};
        float lrun[2] = {0.f, 0.f};
        f32x4 o[2][4];
        #pragma unroll
        for (int qa = 0; qa < 2; qa++)
            #pragma unroll
            for (int nc = 0; nc < 4; nc++) o[qa][nc] = (f32x4){0.f, 0.f, 0.f, 0.f};

        for (int ci = cbeg; ci < cend; ++ci) {
            const int s0 = ci * 64;
            bf16x8 kf[4][2];
            #pragma unroll
            for (int sc = 0; sc < 4; sc++) {
                const unsigned short* kp = kbase + (size_t)(s0 + sc * 16 + c) * 3072 + g * 8;
                kf[sc][0] = *(const bf16x8*)kp;
                kf[sc][1] = *(const bf16x8*)(kp + 32);
            }
            bf16x8 vf[4][2];
            #pragma unroll
            for (int nc = 0; nc < 4; nc++)
                #pragma unroll
                for (int ks = 0; ks < 2; ks++)
                    vf[nc][ks] = *(const bf16x8*)(vtb + (size_t)(nc * 16 + c) * Tn
                                                  + s0 + ks * 32 + g * 8);

            f32x4 sacc[2][4];
            #pragma unroll
            for (int qa = 0; qa < 2; qa++)
                #pragma unroll
                for (int sc = 0; sc < 4; sc++) {
                    f32x4 z = (f32x4){0.f, 0.f, 0.f, 0.f};
                    z = __builtin_amdgcn_mfma_f32_16x16x32_bf16(kf[sc][0], qf[qa][0], z, 0, 0, 0);
                    z = __builtin_amdgcn_mfma_f32_16x16x32_bf16(kf[sc][1], qf[qa][1], z, 0, 0, 0);
                    sacc[qa][sc] = z;
                }

            uint32_t dw[2][4][2];
            #pragma unroll
            for (int qa = 0; qa < 2; qa++) {
                const int q = t0 + qa * 16 + c;
                float pm[4][4];
                const bool needMask = (s0 + 63 > t0 + qa * 16);
                #pragma unroll
                for (int sc = 0; sc < 4; sc++)
                    #pragma unroll
                    for (int r = 0; r < 4; r++) {
                        float v = sacc[qa][sc][r] * SCL;
                        if (needMask && (s0 + sc * 16 + 4 * g + r > q)) v = -1e30f;
                        pm[sc][r] = v;
                    }
                float tmax = pm[0][0];
                #pragma unroll
                for (int sc = 0; sc < 4; sc++)
                    #pragma unroll
                    for (int r = 0; r < 4; r++) tmax = fmaxf(tmax, pm[sc][r]);
                tmax = fmaxf(tmax, __shfl_xor(tmax, 16));
                tmax = fmaxf(tmax, __shfl_xor(tmax, 32));
                float mnew = fmaxf(mrun[qa], tmax);
                float corr = EXP2(mrun[qa] - mnew);
                mrun[qa] = mnew;
                float csum = 0.f;
                #pragma unroll
                for (int sc = 0; sc < 4; sc++)
                    #pragma unroll
                    for (int r = 0; r < 4; r++) {
                        float p = EXP2(pm[sc][r] - mnew);
                        pm[sc][r] = p;
                        csum += p;
                    }
                csum += __shfl_xor(csum, 16);
                csum += __shfl_xor(csum, 32);
                lrun[qa] = lrun[qa] * corr + csum;
                float cb[4];
                #pragma unroll
                for (int r = 0; r < 4; r++) cb[r] = __shfl(corr, 4 * g + r);
                #pragma unroll
                for (int nc = 0; nc < 4; nc++)
                    #pragma unroll
                    for (int r = 0; r < 4; r++) o[qa][nc][r] *= cb[r];
                #pragma unroll
                for (int sc = 0; sc < 4; sc++) {
                    dw[qa][sc][0] = pk2bf(pm[sc][0], pm[sc][1]);
                    dw[qa][sc][1] = pk2bf(pm[sc][2], pm[sc][3]);
                }
            }

            #pragma unroll
            for (int qa = 0; qa < 2; qa++)
                #pragma unroll
                for (int sc = 0; sc < 4; sc++) {
                    u32x2 wv = { dw[qa][sc][0], dw[qa][sc][1] };
                    *(u32x2*)&Psh[wave][qa][c][sc * 8 + 2 * g] = wv;
                }
            #pragma unroll
            for (int ks = 0; ks < 2; ks++) {
                #pragma unroll
                for (int qa = 0; qa < 2; qa++) {
                    u32x4 pd = *(const u32x4*)&Psh[wave][qa][c][ks * 16 + 4 * g];
                    bf16x8 pa = __builtin_bit_cast(bf16x8, pd);
                    #pragma unroll
                    for (int nc = 0; nc < 4; nc++)
                        o[qa][nc] = __builtin_amdgcn_mfma_f32_16x16x32_bf16(
                            pa, vf[nc][ks], o[qa][nc], 0, 0, 0);
                }
            }
        }

        // ---- split-K merge ----
        f32x4 oS[4], oX[4];
        float mS, lS, mX, lX;
        if (wave == 0) {
            #pragma unroll
            for (int nc = 0; nc < 4; nc++) { oS[nc] = o[0][nc]; oX[nc] = o[1][nc]; }
            mS = mrun[0]; lS = lrun[0]; mX = mrun[1]; lX = lrun[1];
        } else {
            #pragma unroll
            for (int nc = 0; nc < 4; nc++) { oS[nc] = o[1][nc]; oX[nc] = o[0][nc]; }
            mS = mrun[1]; lS = lrun[1]; mX = mrun[0]; lX = lrun[0];
        }
        #pragma unroll
        for (int nc = 0; nc < 4; nc++)
            *(f32x4*)&Osh[wave][nc][lane][0] = oX[nc];
        Msh[wave][lane] = mX;
        Lsh[wave][lane] = lX;
        __syncthreads();
        const int pw = wave ^ 1;
        float mP = Msh[pw][lane];
        float lP = Lsh[pw][lane];
        float mM = fmaxf(mS, mP);
        float cS = EXP2(mS - mM);
        float cP = EXP2(mP - mM);
        float rl = 1.0f / (lS * cS + lP * cP);
        float cbS[4], cbP[4], lb[4];
        #pragma unroll
        for (int r = 0; r < 4; r++) {
            cbS[r] = __shfl(cS, 4 * g + r);
            cbP[r] = __shfl(cP, 4 * g + r);
            lb[r]  = __shfl(rl, 4 * g + r);
        }
        #pragma unroll
        for (int nc = 0; nc < 4; nc++) {
            f32x4 oP = *(const f32x4*)&Osh[pw][nc][lane][0];
            #pragma unroll
            for (int r = 0; r < 4; r++) {
                const int trow = t0 + wave * 16 + 4 * g + r;
                float val = (oS[nc][r] * cbS[r] + oP[r] * cbP[r]) * lb[r];
                ctx[(size_t)(b * Tn + trow) * 1024 + h * 64 + nc * 16 + c] = f2bf(val);
            }
        }
        __syncthreads();
    }
}

// ---------------- launch ----------------
extern "C" void kernel_launch(void* const* d_in, const int* in_sizes, int n_in,
                              void* d_out, int out_size, void* d_ws, size_t ws_size,
                              hipStream_t stream) {
    const float* x   = (const float*)d_in[0];
    const float* Wq  = (const float*)d_in[1];
    const float* Wk  = (const float*)d_in[2];
    const float* Wv  = (const float*)d_in[3];
    const float* Wo  = (const float*)d_in[4];
    const float* bo  = (const float*)d_in[5];
    const float* W1  = (const float*)d_in[6];
    const float* b1  = (const float*)d_in[7];
    const float* W2  = (const float*)d_in[8];
    const float* b2  = (const float*)d_in[9];
    const float* g1  = (const float*)d_in[10];
    const float* be1 = (const float*)d_in[11];
    const float* g2  = (const float*)d_in[12];
    const float* be2 = (const float*)d_in[13];

    char* ws = (char*)d_ws;
    unsigned short* wqkv = (unsigned short*)ws;  ws += (size_t)3072 * 1024 * 2;
    unsigned short* wo   = (unsigned short*)ws;  ws += (size_t)1024 * 1024 * 2;
    unsigned short* w1   = (unsigned short*)ws;  ws += (size_t)3072 * 1024 * 2;
    unsigned short* w2   = (unsigned short*)ws;  ws += (size_t)1024 * 3072 * 2;
    unsigned short* bufA = (unsigned short*)ws;  ws += (size_t)Mrows * 1024 * 2; // xn1 / ctx / h2
    unsigned short* bufB = (unsigned short*)ws;  ws += (size_t)Mrows * 3072 * 2; // qkv / ffh

    float* xout = (float*)d_out;           // x1 lives here after out-proj
    unsigned short* vt = (unsigned short*)d_out;   // V^T parks in dead d_out

    // weight prep (single fused launch)
    cast_all_kernel<<<40960, 256, 0, stream>>>(Wq, Wk, Wv, Wo, W1, W2,
                                               wqkv, wo, w1, w2);

    // xn1 = LN(x)
    ln_kernel<<<Mrows, 256, 0, stream>>>(x, g1, be1, bufA);
    // qkv = xn1 @ Wqkv^T
    gemm_bt<0><<<dim3(32, 24), 512, 0, stream>>>(bufA, wqkv, bufB, nullptr, nullptr,
                                                 Mrows, 3072, 1024);
    // vt = V^T
    transpose_v_kernel<<<dim3(Tn / 64, 2 * NHn), 256, 0, stream>>>(bufB, vt);
    // ctx = attention(qkv, vt)
    attn_kernel<<<dim3(1024), 128, 0, stream>>>(bufB, vt, bufA);
    // x1 = x + ctx @ Wo^T + bo   (f32, into d_out; vt dead afterwards)
    gemm_bt<1><<<dim3(32, 8), 512, 0, stream>>>(bufA, wo, xout, bo, x,
                                                Mrows, 1024, 1024);
    // h2 = LN(x1)
    ln_kernel<<<Mrows, 256, 0, stream>>>(xout, g2, be2, bufA);
    // ffh = relu(h2 @ W1^T + b1)
    gemm_bt<2><<<dim3(32, 24), 512, 0, stream>>>(bufA, w1, bufB, b1, nullptr,
                                                 Mrows, 3072, 1024);
    // out = x1 + ffh @ W2^T + b2  (in-place residual from d_out)
    gemm_bt<1><<<dim3(32, 8), 512, 0, stream>>>(bufB, w2, xout, b2, (const float*)xout,
                                                Mrows, 1024, 3072);
}

// Round 22
// 230.301 us; speedup vs baseline: 1.0887x; 1.0160x over previous
//
#include <hip/hip_runtime.h>
#include <stdint.h>

// ---- problem constants ----
#define Tn   2048
#define Cn   1024
#define NHn  16
#define Hn   64
#define FFn  3072
#define Mrows 4096           // B*T
#define LNEPS 1e-6f

#if __has_builtin(__builtin_amdgcn_exp2f)
#define EXP2(x) __builtin_amdgcn_exp2f(x)
#else
#define EXP2(x) exp2f(x)
#endif

typedef float f32x4 __attribute__((ext_vector_type(4)));
typedef __bf16 bf16x8 __attribute__((ext_vector_type(8)));
typedef unsigned short us8 __attribute__((ext_vector_type(8)));
typedef unsigned short us4 __attribute__((ext_vector_type(4)));
typedef unsigned int u32x4 __attribute__((ext_vector_type(4)));
typedef unsigned int u32x2 __attribute__((ext_vector_type(2)));

__device__ __forceinline__ unsigned short f2bf(float f) {
    return __builtin_bit_cast(unsigned short, (__bf16)f);
}

__device__ __forceinline__ uint32_t pk2bf(float lo, float hi) {
    return (uint32_t)f2bf(lo) | ((uint32_t)f2bf(hi) << 16);
}

__device__ __forceinline__ void gl_lds16(const void* g, void* l) {
    __builtin_amdgcn_global_load_lds(
        (const __attribute__((address_space(1))) void*)g,
        (__attribute__((address_space(3))) void*)l, 16, 0, 0);
}

// ---------------- weight prep (all four casts fused into one launch) ----------------
#define CQ  (3072 * 1024)
#define CWO (1024 * 1024)
#define CW1 (3072 * 1024)
__global__ __launch_bounds__(256) void cast_all_kernel(
    const float* __restrict__ Wq, const float* __restrict__ Wk,
    const float* __restrict__ Wv, const float* __restrict__ Wo,
    const float* __restrict__ W1, const float* __restrict__ W2,
    unsigned short* __restrict__ wqkv, unsigned short* __restrict__ wo,
    unsigned short* __restrict__ w1,   unsigned short* __restrict__ w2)
{
    int idx = blockIdx.x * 256 + threadIdx.x;
    if (idx < CQ) {
        int n = idx >> 10, cc = idx & 1023;
        const float* W = (n < 1024) ? Wq : ((n < 2048) ? Wk : Wv);
        int nn = n & 1023;
        wqkv[idx] = f2bf(W[(size_t)((nn >> 6) * 1024 + cc) * 64 + (nn & 63)]);
    } else if (idx < CQ + CWO) {
        int j = idx - CQ;
        wo[j] = f2bf(Wo[j]);
    } else if (idx < CQ + CWO + CW1) {
        int j = idx - CQ - CWO;
        w1[j] = f2bf(W1[j]);
    } else {
        int j = idx - CQ - CWO - CW1;
        w2[j] = f2bf(W2[j]);
    }
}

// ---------------- layernorm (torch: ddof=1, eps on std) ----------------
__global__ __launch_bounds__(256) void ln_kernel(
    const float* __restrict__ xin, const float* __restrict__ gamma,
    const float* __restrict__ beta, unsigned short* __restrict__ out)
{
    const int row = blockIdx.x;
    const int tid = threadIdx.x;
    const float4 v = ((const float4*)(xin + (size_t)row * Cn))[tid];
    float s  = v.x + v.y + v.z + v.w;
    float ss = v.x*v.x + v.y*v.y + v.z*v.z + v.w*v.w;
    #pragma unroll
    for (int off = 1; off < 64; off <<= 1) {
        s  += __shfl_xor(s, off);
        ss += __shfl_xor(ss, off);
    }
    __shared__ float red[8];
    const int wave = tid >> 6, lane = tid & 63;
    if (lane == 0) { red[wave] = s; red[4 + wave] = ss; }
    __syncthreads();
    float S  = red[0] + red[1] + red[2] + red[3];
    float SS = red[4] + red[5] + red[6] + red[7];
    float mean = S * (1.0f / 1024.0f);
    float var  = (SS - 1024.0f * mean * mean) * (1.0f / 1023.0f);
    var = fmaxf(var, 0.0f);
    float inv = 1.0f / (sqrtf(var) + LNEPS);
    const float4 gv = ((const float4*)gamma)[tid];
    const float4 bv = ((const float4*)beta)[tid];
    us4 ov;
    ov[0] = f2bf(gv.x * (v.x - mean) * inv + bv.x);
    ov[1] = f2bf(gv.y * (v.y - mean) * inv + bv.y);
    ov[2] = f2bf(gv.z * (v.z - mean) * inv + bv.z);
    ov[3] = f2bf(gv.w * (v.w - mean) * inv + bv.w);
    *(us4*)(out + (size_t)row * Cn + tid * 4) = ov;
}

// ---------------- GEMM 128x128 (R14 proven) + fused V^T epilogue for MODE 0 ----------
// MODE 0 blocks with n0 >= 2048 (the V third of qkv) write acc directly in V^T layout:
//   col-2048 = h*64+d ; row = b*2048+t ; vt[((b*16+h)*64+d)*2048 + t], us4 of 4 consec t
// (rowb multiple of 4; 128-row tiles never straddle the T=2048 boundary).
template<int MODE>
__global__ __launch_bounds__(512) void gemm_bt(
    const unsigned short* __restrict__ A,
    const unsigned short* __restrict__ Bt,
    void* Cout,                      // may alias resid (FF2) -> no restrict
    const float* __restrict__ bias,
    const float* resid,
    unsigned short* __restrict__ vtOut,
    int M, int N, int K)
{
    __shared__ unsigned short lds[3][8192];   // per buf: A[128][32] @0, B[128][32] @4096
    const int tid  = threadIdx.x;
    const int wave = tid >> 6, lane = tid & 63;
    const int g = lane >> 4, c = lane & 15;
    const int wr = wave >> 2, wc = wave & 3;
    const int m0 = blockIdx.x * 128, n0 = blockIdx.y * 128;

    f32x4 acc[4][2];
    #pragma unroll
    for (int i = 0; i < 4; i++)
        #pragma unroll
        for (int j = 0; j < 2; j++) acc[i][j] = (f32x4){0.f, 0.f, 0.f, 0.f};

    const int srow = wave * 16 + (lane >> 2);
    const int scol = (((lane & 3) ^ ((lane >> 3) & 3)) * 8);
    const unsigned short* sA = A  + (size_t)(m0 + srow) * K + scol;
    const unsigned short* sB = Bt + (size_t)(n0 + srow) * K + scol;
    const int wdst = wave * 512;

    auto STAGE = [&](int t, int b) {
        const int ko = t * 32;
        gl_lds16(sA + ko, &lds[b][wdst]);
        gl_lds16(sB + ko, &lds[b][4096 + wdst]);
    };

    STAGE(0, 0);
    STAGE(1, 1);
    asm volatile("s_waitcnt vmcnt(2)" ::: "memory");
    __builtin_amdgcn_s_barrier();

    const int jsw = (g ^ ((c >> 1) & 3)) * 8;

    const int NT = K >> 5;
    int cur = 0;
    for (int t = 0; t < NT; ++t) {
        const bool pf = (t + 2 < NT);
        if (pf) { int b = cur + 2; if (b >= 3) b -= 3; STAGE(t + 2, b); }

        bf16x8 af[4], bfr[2];
        #pragma unroll
        for (int mi = 0; mi < 4; mi++)
            af[mi]  = *(const bf16x8*)&lds[cur][(wr * 64 + mi * 16 + c) * 32 + jsw];
        #pragma unroll
        for (int ni = 0; ni < 2; ni++)
            bfr[ni] = *(const bf16x8*)&lds[cur][4096 + (wc * 32 + ni * 16 + c) * 32 + jsw];
        __builtin_amdgcn_s_setprio(1);
        #pragma unroll
        for (int mi = 0; mi < 4; mi++)
            #pragma unroll
            for (int ni = 0; ni < 2; ni++)
                acc[mi][ni] = __builtin_amdgcn_mfma_f32_16x16x32_bf16(
                    af[mi], bfr[ni], acc[mi][ni], 0, 0, 0);
        __builtin_amdgcn_s_setprio(0);

        if (pf) asm volatile("s_waitcnt vmcnt(2)" ::: "memory");
        else    asm volatile("s_waitcnt vmcnt(0)" ::: "memory");
        __builtin_amdgcn_s_barrier();
        cur = (cur == 2) ? 0 : cur + 1;
    }

    const int rowb = m0 + wr * 64 + g * 4;
    const int colb = n0 + wc * 32 + c;

    if (MODE == 0 && n0 >= 2048) {
        // fused V^T write
        #pragma unroll
        for (int mi = 0; mi < 4; mi++) {
            const int row = rowb + mi * 16;
            const int bb = row >> 11, tt = row & 2047;
            #pragma unroll
            for (int ni = 0; ni < 2; ni++) {
                const int cc2 = colb + ni * 16 - 2048;       // h*64 + d
                us4 ov;
                #pragma unroll
                for (int r = 0; r < 4; r++) ov[r] = f2bf(acc[mi][ni][r]);
                *(us4*)(vtOut + ((size_t)(bb * 16 + (cc2 >> 6)) * 64 + (cc2 & 63)) * 2048 + tt) = ov;
            }
        }
        return;
    }

    #pragma unroll
    for (int mi = 0; mi < 4; mi++) {
        #pragma unroll
        for (int ni = 0; ni < 2; ni++) {
            const int col = colb + ni * 16;
            float bv = (MODE == 1 || MODE == 2) ? bias[col] : 0.f;
            #pragma unroll
            for (int r = 0; r < 4; r++) {
                const int row = rowb + mi * 16 + r;
                float v = acc[mi][ni][r];
                if (MODE == 1) {
                    float res = resid[(size_t)row * N + col];
                    ((float*)Cout)[(size_t)row * N + col] = v + bv + res;
                } else if (MODE == 2) {
                    float t = v + bv;
                    t = t > 0.f ? t : 0.f;
                    ((unsigned short*)Cout)[(size_t)row * N + col] = f2bf(t);
                } else {
                    ((unsigned short*)Cout)[(size_t)row * N + col] = f2bf(v);
                }
            }
        }
    }
}

// ---------------- flash attention (R18 proven best: pair-map split-K) ----------------
__global__ __launch_bounds__(128, 2) void attn_kernel(
    const unsigned short* __restrict__ qkv,
    const unsigned short* __restrict__ vt,
    unsigned short* __restrict__ ctx)
{
    const float SCL = 0.125f * 1.44269504088896f;
    __shared__ float Osh[2][4][64][4];
    __shared__ float Msh[2][64];
    __shared__ float Lsh[2][64];
    __shared__ uint32_t Psh[2][2][16][36];

    const int tid  = threadIdx.x;
    const int wave = tid >> 6, lane = tid & 63;
    const int g = lane >> 4, c = lane & 15;
    const int l = blockIdx.x;
    const int pj = l >> 5;
    const int bh = ((l & 7) << 2) | ((l >> 3) & 3);
    const int b = bh >> 4, h = bh & 15;
    const unsigned short* base  = qkv + (size_t)b * Tn * 3072;
    const unsigned short* qbase = base + h * 64;
    const unsigned short* kbase = base + 1024 + h * 64;
    const unsigned short* vtb   = vt + (size_t)bh * (Hn * Tn);

    for (int half = 0; half < 2; ++half) {
        const int tileIdx = half ? (63 - pj) : pj;
        const int t0 = tileIdx * 32;
        const int nch  = (t0 + 95) >> 6;
        const int nh0  = (nch + 1) >> 1;
        const int cbeg = wave ? nh0 : 0;
        const int cend = wave ? nch : nh0;

        bf16x8 qf[2][2];
        #pragma unroll
        for (int qa = 0; qa < 2; qa++) {
            const unsigned short* qp = qbase + (size_t)(t0 + qa * 16 + c) * 3072 + g * 8;
            qf[qa][0] = *(const bf16x8*)qp;
            qf[qa][1] = *(const bf16x8*)(qp + 32);
        }

        float mrun[2] = {-1e30f, -1e30f};
        float lrun[2] = {0.f, 0.f};
        f32x4 o[2][4];
        #pragma unroll
        for (int qa = 0; qa < 2; qa++)
            #pragma unroll
            for (int nc = 0; nc < 4; nc++) o[qa][nc] = (f32x4){0.f, 0.f, 0.f, 0.f};

        for (int ci = cbeg; ci < cend; ++ci) {
            const int s0 = ci * 64;
            bf16x8 kf[4][2];
            #pragma unroll
            for (int sc = 0; sc < 4; sc++) {
                const unsigned short* kp = kbase + (size_t)(s0 + sc * 16 + c) * 3072 + g * 8;
                kf[sc][0] = *(const bf16x8*)kp;
                kf[sc][1] = *(const bf16x8*)(kp + 32);
            }
            bf16x8 vf[4][2];
            #pragma unroll
            for (int nc = 0; nc < 4; nc++)
                #pragma unroll
                for (int ks = 0; ks < 2; ks++)
                    vf[nc][ks] = *(const bf16x8*)(vtb + (size_t)(nc * 16 + c) * Tn
                                                  + s0 + ks * 32 + g * 8);

            f32x4 sacc[2][4];
            #pragma unroll
            for (int qa = 0; qa < 2; qa++)
                #pragma unroll
                for (int sc = 0; sc < 4; sc++) {
                    f32x4 z = (f32x4){0.f, 0.f, 0.f, 0.f};
                    z = __builtin_amdgcn_mfma_f32_16x16x32_bf16(kf[sc][0], qf[qa][0], z, 0, 0, 0);
                    z = __builtin_amdgcn_mfma_f32_16x16x32_bf16(kf[sc][1], qf[qa][1], z, 0, 0, 0);
                    sacc[qa][sc] = z;
                }

            uint32_t dw[2][4][2];
            #pragma unroll
            for (int qa = 0; qa < 2; qa++) {
                const int q = t0 + qa * 16 + c;
                float pm[4][4];
                const bool needMask = (s0 + 63 > t0 + qa * 16);
                #pragma unroll
                for (int sc = 0; sc < 4; sc++)
                    #pragma unroll
                    for (int r = 0; r < 4; r++) {
                        float v = sacc[qa][sc][r] * SCL;
                        if (needMask && (s0 + sc * 16 + 4 * g + r > q)) v = -1e30f;
                        pm[sc][r] = v;
                    }
                float tmax = pm[0][0];
                #pragma unroll
                for (int sc = 0; sc < 4; sc++)
                    #pragma unroll
                    for (int r = 0; r < 4; r++) tmax = fmaxf(tmax, pm[sc][r]);
                tmax = fmaxf(tmax, __shfl_xor(tmax, 16));
                tmax = fmaxf(tmax, __shfl_xor(tmax, 32));
                float mnew = fmaxf(mrun[qa], tmax);
                float corr = EXP2(mrun[qa] - mnew);
                mrun[qa] = mnew;
                float csum = 0.f;
                #pragma unroll
                for (int sc = 0; sc < 4; sc++)
                    #pragma unroll
                    for (int r = 0; r < 4; r++) {
                        float p = EXP2(pm[sc][r] - mnew);
                        pm[sc][r] = p;
                        csum += p;
                    }
                csum += __shfl_xor(csum, 16);
                csum += __shfl_xor(csum, 32);
                lrun[qa] = lrun[qa] * corr + csum;
                float cb[4];
                #pragma unroll
                for (int r = 0; r < 4; r++) cb[r] = __shfl(corr, 4 * g + r);
                #pragma unroll
                for (int nc = 0; nc < 4; nc++)
                    #pragma unroll
                    for (int r = 0; r < 4; r++) o[qa][nc][r] *= cb[r];
                #pragma unroll
                for (int sc = 0; sc < 4; sc++) {
                    dw[qa][sc][0] = pk2bf(pm[sc][0], pm[sc][1]);
                    dw[qa][sc][1] = pk2bf(pm[sc][2], pm[sc][3]);
                }
            }

            #pragma unroll
            for (int qa = 0; qa < 2; qa++)
                #pragma unroll
                for (int sc = 0; sc < 4; sc++) {
                    u32x2 wv = { dw[qa][sc][0], dw[qa][sc][1] };
                    *(u32x2*)&Psh[wave][qa][c][sc * 8 + 2 * g] = wv;
                }
            #pragma unroll
            for (int ks = 0; ks < 2; ks++) {
                #pragma unroll
                for (int qa = 0; qa < 2; qa++) {
                    u32x4 pd = *(const u32x4*)&Psh[wave][qa][c][ks * 16 + 4 * g];
                    bf16x8 pa = __builtin_bit_cast(bf16x8, pd);
                    #pragma unroll
                    for (int nc = 0; nc < 4; nc++)
                        o[qa][nc] = __builtin_amdgcn_mfma_f32_16x16x32_bf16(
                            pa, vf[nc][ks], o[qa][nc], 0, 0, 0);
                }
            }
        }

        // ---- split-K merge ----
        f32x4 oS[4], oX[4];
        float mS, lS, mX, lX;
        if (wave == 0) {
            #pragma unroll
            for (int nc = 0; nc < 4; nc++) { oS[nc] = o[0][nc]; oX[nc] = o[1][nc]; }
            mS = mrun[0]; lS = lrun[0]; mX = mrun[1]; lX = lrun[1];
        } else {
            #pragma unroll
            for (int nc = 0; nc < 4; nc++) { oS[nc] = o[1][nc]; oX[nc] = o[0][nc]; }
            mS = mrun[1]; lS = lrun[1]; mX = mrun[0]; lX = lrun[0];
        }
        #pragma unroll
        for (int nc = 0; nc < 4; nc++)
            *(f32x4*)&Osh[wave][nc][lane][0] = oX[nc];
        Msh[wave][lane] = mX;
        Lsh[wave][lane] = lX;
        __syncthreads();
        const int pw = wave ^ 1;
        float mP = Msh[pw][lane];
        float lP = Lsh[pw][lane];
        float mM = fmaxf(mS, mP);
        float cS = EXP2(mS - mM);
        float cP = EXP2(mP - mM);
        float rl = 1.0f / (lS * cS + lP * cP);
        float cbS[4], cbP[4], lb[4];
        #pragma unroll
        for (int r = 0; r < 4; r++) {
            cbS[r] = __shfl(cS, 4 * g + r);
            cbP[r] = __shfl(cP, 4 * g + r);
            lb[r]  = __shfl(rl, 4 * g + r);
        }
        #pragma unroll
        for (int nc = 0; nc < 4; nc++) {
            f32x4 oP = *(const f32x4*)&Osh[pw][nc][lane][0];
            #pragma unroll
            for (int r = 0; r < 4; r++) {
                const int trow = t0 + wave * 16 + 4 * g + r;
                float val = (oS[nc][r] * cbS[r] + oP[r] * cbP[r]) * lb[r];
                ctx[(size_t)(b * Tn + trow) * 1024 + h * 64 + nc * 16 + c] = f2bf(val);
            }
        }
        __syncthreads();
    }
}

// ---------------- launch ----------------
extern "C" void kernel_launch(void* const* d_in, const int* in_sizes, int n_in,
                              void* d_out, int out_size, void* d_ws, size_t ws_size,
                              hipStream_t stream) {
    const float* x   = (const float*)d_in[0];
    const float* Wq  = (const float*)d_in[1];
    const float* Wk  = (const float*)d_in[2];
    const float* Wv  = (const float*)d_in[3];
    const float* Wo  = (const float*)d_in[4];
    const float* bo  = (const float*)d_in[5];
    const float* W1  = (const float*)d_in[6];
    const float* b1  = (const float*)d_in[7];
    const float* W2  = (const float*)d_in[8];
    const float* b2  = (const float*)d_in[9];
    const float* g1  = (const float*)d_in[10];
    const float* be1 = (const float*)d_in[11];
    const float* g2  = (const float*)d_in[12];
    const float* be2 = (const float*)d_in[13];

    char* ws = (char*)d_ws;
    unsigned short* wqkv = (unsigned short*)ws;  ws += (size_t)3072 * 1024 * 2;
    unsigned short* wo   = (unsigned short*)ws;  ws += (size_t)1024 * 1024 * 2;
    unsigned short* w1   = (unsigned short*)ws;  ws += (size_t)3072 * 1024 * 2;
    unsigned short* w2   = (unsigned short*)ws;  ws += (size_t)1024 * 3072 * 2;
    unsigned short* bufA = (unsigned short*)ws;  ws += (size_t)Mrows * 1024 * 2; // xn1 / ctx / h2
    unsigned short* bufB = (unsigned short*)ws;  ws += (size_t)Mrows * 3072 * 2; // qkv / ffh

    float* xout = (float*)d_out;           // x1 lives here after out-proj
    unsigned short* vt = (unsigned short*)d_out;   // V^T parks in dead d_out

    // weight prep (single fused launch)
    cast_all_kernel<<<40960, 256, 0, stream>>>(Wq, Wk, Wv, Wo, W1, W2,
                                               wqkv, wo, w1, w2);

    // xn1 = LN(x)
    ln_kernel<<<Mrows, 256, 0, stream>>>(x, g1, be1, bufA);
    // qkv = xn1 @ Wqkv^T  (V third written directly as V^T into vt)
    gemm_bt<0><<<dim3(32, 24), 512, 0, stream>>>(bufA, wqkv, bufB, nullptr, nullptr,
                                                 vt, Mrows, 3072, 1024);
    // ctx = attention(qkv, vt)
    attn_kernel<<<dim3(1024), 128, 0, stream>>>(bufB, vt, bufA);
    // x1 = x + ctx @ Wo^T + bo   (f32, into d_out; vt dead afterwards)
    gemm_bt<1><<<dim3(32, 8), 512, 0, stream>>>(bufA, wo, xout, bo, x,
                                                nullptr, Mrows, 1024, 1024);
    // h2 = LN(x1)
    ln_kernel<<<Mrows, 256, 0, stream>>>(xout, g2, be2, bufA);
    // ffh = relu(h2 @ W1^T + b1)
    gemm_bt<2><<<dim3(32, 24), 512, 0, stream>>>(bufA, w1, bufB, b1, nullptr,
                                                 nullptr, Mrows, 3072, 1024);
    // out = x1 + ffh @ W2^T + b2  (in-place residual from d_out)
    gemm_bt<1><<<dim3(32, 8), 512, 0, stream>>>(bufB, w2, xout, b2, (const float*)xout,
                                                nullptr, Mrows, 1024, 3072);
}

// Round 23
// 229.128 us; speedup vs baseline: 1.0943x; 1.0051x over previous
//
#include <hip/hip_runtime.h>
#include <stdint.h>

// ---- problem constants ----
#define Tn   2048
#define Cn   1024
#define NHn  16
#define Hn   64
#define FFn  3072
#define Mrows 4096           // B*T
#define LNEPS 1e-6f

#if __has_builtin(__builtin_amdgcn_exp2f)
#define EXP2(x) __builtin_amdgcn_exp2f(x)
#else
#define EXP2(x) exp2f(x)
#endif

typedef float f32x4 __attribute__((ext_vector_type(4)));
typedef __bf16 bf16x8 __attribute__((ext_vector_type(8)));
typedef unsigned short us8 __attribute__((ext_vector_type(8)));
typedef unsigned short us4 __attribute__((ext_vector_type(4)));
typedef unsigned int u32x4 __attribute__((ext_vector_type(4)));
typedef unsigned int u32x2 __attribute__((ext_vector_type(2)));

__device__ __forceinline__ unsigned short f2bf(float f) {
    return __builtin_bit_cast(unsigned short, (__bf16)f);
}

__device__ __forceinline__ uint32_t pk2bf(float lo, float hi) {
    return (uint32_t)f2bf(lo) | ((uint32_t)f2bf(hi) << 16);
}

__device__ __forceinline__ void gl_lds16(const void* g, void* l) {
    __builtin_amdgcn_global_load_lds(
        (const __attribute__((address_space(1))) void*)g,
        (__attribute__((address_space(3))) void*)l, 16, 0, 0);
}

// ---------------- weight prep (fused, 4 elems/thread) ----------------
// region 0: wqkv [3072][1024] <- gather (stride-64) from Wq/Wk/Wv [NH][C][H]
// regions 1-3: contiguous casts (float4 load + us4 store).  All region sizes
// are multiples of 4 -> no 4-group straddles a region boundary.
#define CQ  (3072 * 1024)
#define CWO (1024 * 1024)
#define CW1 (3072 * 1024)
__global__ __launch_bounds__(256) void cast_all_kernel(
    const float* __restrict__ Wq, const float* __restrict__ Wk,
    const float* __restrict__ Wv, const float* __restrict__ Wo,
    const float* __restrict__ W1, const float* __restrict__ W2,
    unsigned short* __restrict__ wqkv, unsigned short* __restrict__ wo,
    unsigned short* __restrict__ w1,   unsigned short* __restrict__ w2)
{
    const int idx4 = (blockIdx.x * 256 + threadIdx.x) * 4;
    if (idx4 < CQ) {
        int n = idx4 >> 10, cc = idx4 & 1023;      // same n for all 4 (cc <= 1020)
        const float* W = (n < 1024) ? Wq : ((n < 2048) ? Wk : Wv);
        int nn = n & 1023;
        const float* basep = W + (size_t)((nn >> 6) * 1024 + cc) * 64 + (nn & 63);
        us4 ov;
        #pragma unroll
        for (int e = 0; e < 4; e++) ov[e] = f2bf(basep[(size_t)e * 64]);
        *(us4*)(wqkv + idx4) = ov;
    } else {
        const float* src; unsigned short* dst; int j;
        if (idx4 < CQ + CWO)            { j = idx4 - CQ;             src = Wo; dst = wo; }
        else if (idx4 < CQ + CWO + CW1) { j = idx4 - CQ - CWO;       src = W1; dst = w1; }
        else                            { j = idx4 - CQ - CWO - CW1; src = W2; dst = w2; }
        f32x4 v = *(const f32x4*)(src + j);
        us4 ov;
        #pragma unroll
        for (int e = 0; e < 4; e++) ov[e] = f2bf(v[e]);
        *(us4*)(dst + j) = ov;
    }
}

// ---------------- layernorm (torch: ddof=1, eps on std) ----------------
__global__ __launch_bounds__(256) void ln_kernel(
    const float* __restrict__ xin, const float* __restrict__ gamma,
    const float* __restrict__ beta, unsigned short* __restrict__ out)
{
    const int row = blockIdx.x;
    const int tid = threadIdx.x;
    const float4 v = ((const float4*)(xin + (size_t)row * Cn))[tid];
    float s  = v.x + v.y + v.z + v.w;
    float ss = v.x*v.x + v.y*v.y + v.z*v.z + v.w*v.w;
    #pragma unroll
    for (int off = 1; off < 64; off <<= 1) {
        s  += __shfl_xor(s, off);
        ss += __shfl_xor(ss, off);
    }
    __shared__ float red[8];
    const int wave = tid >> 6, lane = tid & 63;
    if (lane == 0) { red[wave] = s; red[4 + wave] = ss; }
    __syncthreads();
    float S  = red[0] + red[1] + red[2] + red[3];
    float SS = red[4] + red[5] + red[6] + red[7];
    float mean = S * (1.0f / 1024.0f);
    float var  = (SS - 1024.0f * mean * mean) * (1.0f / 1023.0f);
    var = fmaxf(var, 0.0f);
    float inv = 1.0f / (sqrtf(var) + LNEPS);
    const float4 gv = ((const float4*)gamma)[tid];
    const float4 bv = ((const float4*)beta)[tid];
    us4 ov;
    ov[0] = f2bf(gv.x * (v.x - mean) * inv + bv.x);
    ov[1] = f2bf(gv.y * (v.y - mean) * inv + bv.y);
    ov[2] = f2bf(gv.z * (v.z - mean) * inv + bv.z);
    ov[3] = f2bf(gv.w * (v.w - mean) * inv + bv.w);
    *(us4*)(out + (size_t)row * Cn + tid * 4) = ov;
}

// ---------------- GEMM 128x128 (R14 proven) + fused V^T epilogue for MODE 0 ----------
template<int MODE>
__global__ __launch_bounds__(512) void gemm_bt(
    const unsigned short* __restrict__ A,
    const unsigned short* __restrict__ Bt,
    void* Cout,                      // may alias resid (FF2) -> no restrict
    const float* __restrict__ bias,
    const float* resid,
    unsigned short* __restrict__ vtOut,
    int M, int N, int K)
{
    __shared__ unsigned short lds[3][8192];   // per buf: A[128][32] @0, B[128][32] @4096
    const int tid  = threadIdx.x;
    const int wave = tid >> 6, lane = tid & 63;
    const int g = lane >> 4, c = lane & 15;
    const int wr = wave >> 2, wc = wave & 3;
    const int m0 = blockIdx.x * 128, n0 = blockIdx.y * 128;

    f32x4 acc[4][2];
    #pragma unroll
    for (int i = 0; i < 4; i++)
        #pragma unroll
        for (int j = 0; j < 2; j++) acc[i][j] = (f32x4){0.f, 0.f, 0.f, 0.f};

    const int srow = wave * 16 + (lane >> 2);
    const int scol = (((lane & 3) ^ ((lane >> 3) & 3)) * 8);
    const unsigned short* sA = A  + (size_t)(m0 + srow) * K + scol;
    const unsigned short* sB = Bt + (size_t)(n0 + srow) * K + scol;
    const int wdst = wave * 512;

    auto STAGE = [&](int t, int b) {
        const int ko = t * 32;
        gl_lds16(sA + ko, &lds[b][wdst]);
        gl_lds16(sB + ko, &lds[b][4096 + wdst]);
    };

    STAGE(0, 0);
    STAGE(1, 1);
    asm volatile("s_waitcnt vmcnt(2)" ::: "memory");
    __builtin_amdgcn_s_barrier();

    const int jsw = (g ^ ((c >> 1) & 3)) * 8;

    const int NT = K >> 5;
    int cur = 0;
    for (int t = 0; t < NT; ++t) {
        const bool pf = (t + 2 < NT);
        if (pf) { int b = cur + 2; if (b >= 3) b -= 3; STAGE(t + 2, b); }

        bf16x8 af[4], bfr[2];
        #pragma unroll
        for (int mi = 0; mi < 4; mi++)
            af[mi]  = *(const bf16x8*)&lds[cur][(wr * 64 + mi * 16 + c) * 32 + jsw];
        #pragma unroll
        for (int ni = 0; ni < 2; ni++)
            bfr[ni] = *(const bf16x8*)&lds[cur][4096 + (wc * 32 + ni * 16 + c) * 32 + jsw];
        __builtin_amdgcn_s_setprio(1);
        #pragma unroll
        for (int mi = 0; mi < 4; mi++)
            #pragma unroll
            for (int ni = 0; ni < 2; ni++)
                acc[mi][ni] = __builtin_amdgcn_mfma_f32_16x16x32_bf16(
                    af[mi], bfr[ni], acc[mi][ni], 0, 0, 0);
        __builtin_amdgcn_s_setprio(0);

        if (pf) asm volatile("s_waitcnt vmcnt(2)" ::: "memory");
        else    asm volatile("s_waitcnt vmcnt(0)" ::: "memory");
        __builtin_amdgcn_s_barrier();
        cur = (cur == 2) ? 0 : cur + 1;
    }

    const int rowb = m0 + wr * 64 + g * 4;
    const int colb = n0 + wc * 32 + c;

    if (MODE == 0 && n0 >= 2048) {
        // fused V^T write
        #pragma unroll
        for (int mi = 0; mi < 4; mi++) {
            const int row = rowb + mi * 16;
            const int bb = row >> 11, tt = row & 2047;
            #pragma unroll
            for (int ni = 0; ni < 2; ni++) {
                const int cc2 = colb + ni * 16 - 2048;       // h*64 + d
                us4 ov;
                #pragma unroll
                for (int r = 0; r < 4; r++) ov[r] = f2bf(acc[mi][ni][r]);
                *(us4*)(vtOut + ((size_t)(bb * 16 + (cc2 >> 6)) * 64 + (cc2 & 63)) * 2048 + tt) = ov;
            }
        }
        return;
    }

    #pragma unroll
    for (int mi = 0; mi < 4; mi++) {
        #pragma unroll
        for (int ni = 0; ni < 2; ni++) {
            const int col = colb + ni * 16;
            float bv = (MODE == 1 || MODE == 2) ? bias[col] : 0.f;
            #pragma unroll
            for (int r = 0; r < 4; r++) {
                const int row = rowb + mi * 16 + r;
                float v = acc[mi][ni][r];
                if (MODE == 1) {
                    float res = resid[(size_t)row * N + col];
                    ((float*)Cout)[(size_t)row * N + col] = v + bv + res;
                } else if (MODE == 2) {
                    float t = v + bv;
                    t = t > 0.f ? t : 0.f;
                    ((unsigned short*)Cout)[(size_t)row * N + col] = f2bf(t);
                } else {
                    ((unsigned short*)Cout)[(size_t)row * N + col] = f2bf(v);
                }
            }
        }
    }
}

// ---------------- flash attention (R18 proven best: pair-map split-K) ----------------
__global__ __launch_bounds__(128, 2) void attn_kernel(
    const unsigned short* __restrict__ qkv,
    const unsigned short* __restrict__ vt,
    unsigned short* __restrict__ ctx)
{
    const float SCL = 0.125f * 1.44269504088896f;
    __shared__ float Osh[2][4][64][4];
    __shared__ float Msh[2][64];
    __shared__ float Lsh[2][64];
    __shared__ uint32_t Psh[2][2][16][36];

    const int tid  = threadIdx.x;
    const int wave = tid >> 6, lane = tid & 63;
    const int g = lane >> 4, c = lane & 15;
    const int l = blockIdx.x;
    const int pj = l >> 5;
    const int bh = ((l & 7) << 2) | ((l >> 3) & 3);
    const int b = bh >> 4, h = bh & 15;
    const unsigned short* base  = qkv + (size_t)b * Tn * 3072;
    const unsigned short* qbase = base + h * 64;
    const unsigned short* kbase = base + 1024 + h * 64;
    const unsigned short* vtb   = vt + (size_t)bh * (Hn * Tn);

    for (int half = 0; half < 2; ++half) {
        const int tileIdx = half ? (63 - pj) : pj;
        const int t0 = tileIdx * 32;
        const int nch  = (t0 + 95) >> 6;
        const int nh0  = (nch + 1) >> 1;
        const int cbeg = wave ? nh0 : 0;
        const int cend = wave ? nch : nh0;

        bf16x8 qf[2][2];
        #pragma unroll
        for (int qa = 0; qa < 2; qa++) {
            const unsigned short* qp = qbase + (size_t)(t0 + qa * 16 + c) * 3072 + g * 8;
            qf[qa][0] = *(const bf16x8*)qp;
            qf[qa][1] = *(const bf16x8*)(qp + 32);
        }

        float mrun[2] = {-1e30f, -1e30f};
        float lrun[2] = {0.f, 0.f};
        f32x4 o[2][4];
        #pragma unroll
        for (int qa = 0; qa < 2; qa++)
            #pragma unroll
            for (int nc = 0; nc < 4; nc++) o[qa][nc] = (f32x4){0.f, 0.f, 0.f, 0.f};

        for (int ci = cbeg; ci < cend; ++ci) {
            const int s0 = ci * 64;
            bf16x8 kf[4][2];
            #pragma unroll
            for (int sc = 0; sc < 4; sc++) {
                const unsigned short* kp = kbase + (size_t)(s0 + sc * 16 + c) * 3072 + g * 8;
                kf[sc][0] = *(const bf16x8*)kp;
                kf[sc][1] = *(const bf16x8*)(kp + 32);
            }
            bf16x8 vf[4][2];
            #pragma unroll
            for (int nc = 0; nc < 4; nc++)
                #pragma unroll
                for (int ks = 0; ks < 2; ks++)
                    vf[nc][ks] = *(const bf16x8*)(vtb + (size_t)(nc * 16 + c) * Tn
                                                  + s0 + ks * 32 + g * 8);

            f32x4 sacc[2][4];
            #pragma unroll
            for (int qa = 0; qa < 2; qa++)
                #pragma unroll
                for (int sc = 0; sc < 4; sc++) {
                    f32x4 z = (f32x4){0.f, 0.f, 0.f, 0.f};
                    z = __builtin_amdgcn_mfma_f32_16x16x32_bf16(kf[sc][0], qf[qa][0], z, 0, 0, 0);
                    z = __builtin_amdgcn_mfma_f32_16x16x32_bf16(kf[sc][1], qf[qa][1], z, 0, 0, 0);
                    sacc[qa][sc] = z;
                }

            uint32_t dw[2][4][2];
            #pragma unroll
            for (int qa = 0; qa < 2; qa++) {
                const int q = t0 + qa * 16 + c;
                float pm[4][4];
                const bool needMask = (s0 + 63 > t0 + qa * 16);
                #pragma unroll
                for (int sc = 0; sc < 4; sc++)
                    #pragma unroll
                    for (int r = 0; r < 4; r++) {
                        float v = sacc[qa][sc][r] * SCL;
                        if (needMask && (s0 + sc * 16 + 4 * g + r > q)) v = -1e30f;
                        pm[sc][r] = v;
                    }
                float tmax = pm[0][0];
                #pragma unroll
                for (int sc = 0; sc < 4; sc++)
                    #pragma unroll
                    for (int r = 0; r < 4; r++) tmax = fmaxf(tmax, pm[sc][r]);
                tmax = fmaxf(tmax, __shfl_xor(tmax, 16));
                tmax = fmaxf(tmax, __shfl_xor(tmax, 32));
                float mnew = fmaxf(mrun[qa], tmax);
                float corr = EXP2(mrun[qa] - mnew);
                mrun[qa] = mnew;
                float csum = 0.f;
                #pragma unroll
                for (int sc = 0; sc < 4; sc++)
                    #pragma unroll
                    for (int r = 0; r < 4; r++) {
                        float p = EXP2(pm[sc][r] - mnew);
                        pm[sc][r] = p;
                        csum += p;
                    }
                csum += __shfl_xor(csum, 16);
                csum += __shfl_xor(csum, 32);
                lrun[qa] = lrun[qa] * corr + csum;
                float cb[4];
                #pragma unroll
                for (int r = 0; r < 4; r++) cb[r] = __shfl(corr, 4 * g + r);
                #pragma unroll
                for (int nc = 0; nc < 4; nc++)
                    #pragma unroll
                    for (int r = 0; r < 4; r++) o[qa][nc][r] *= cb[r];
                #pragma unroll
                for (int sc = 0; sc < 4; sc++) {
                    dw[qa][sc][0] = pk2bf(pm[sc][0], pm[sc][1]);
                    dw[qa][sc][1] = pk2bf(pm[sc][2], pm[sc][3]);
                }
            }

            #pragma unroll
            for (int qa = 0; qa < 2; qa++)
                #pragma unroll
                for (int sc = 0; sc < 4; sc++) {
                    u32x2 wv = { dw[qa][sc][0], dw[qa][sc][1] };
                    *(u32x2*)&Psh[wave][qa][c][sc * 8 + 2 * g] = wv;
                }
            #pragma unroll
            for (int ks = 0; ks < 2; ks++) {
                #pragma unroll
                for (int qa = 0; qa < 2; qa++) {
                    u32x4 pd = *(const u32x4*)&Psh[wave][qa][c][ks * 16 + 4 * g];
                    bf16x8 pa = __builtin_bit_cast(bf16x8, pd);
                    #pragma unroll
                    for (int nc = 0; nc < 4; nc++)
                        o[qa][nc] = __builtin_amdgcn_mfma_f32_16x16x32_bf16(
                            pa, vf[nc][ks], o[qa][nc], 0, 0, 0);
                }
            }
        }

        // ---- split-K merge ----
        f32x4 oS[4], oX[4];
        float mS, lS, mX, lX;
        if (wave == 0) {
            #pragma unroll
            for (int nc = 0; nc < 4; nc++) { oS[nc] = o[0][nc]; oX[nc] = o[1][nc]; }
            mS = mrun[0]; lS = lrun[0]; mX = mrun[1]; lX = lrun[1];
        } else {
            #pragma unroll
            for (int nc = 0; nc < 4; nc++) { oS[nc] = o[1][nc]; oX[nc] = o[0][nc]; }
            mS = mrun[1]; lS = lrun[1]; mX = mrun[0]; lX = lrun[0];
        }
        #pragma unroll
        for (int nc = 0; nc < 4; nc++)
            *(f32x4*)&Osh[wave][nc][lane][0] = oX[nc];
        Msh[wave][lane] = mX;
        Lsh[wave][lane] = lX;
        __syncthreads();
        const int pw = wave ^ 1;
        float mP = Msh[pw][lane];
        float lP = Lsh[pw][lane];
        float mM = fmaxf(mS, mP);
        float cS = EXP2(mS - mM);
        float cP = EXP2(mP - mM);
        float rl = 1.0f / (lS * cS + lP * cP);
        float cbS[4], cbP[4], lb[4];
        #pragma unroll
        for (int r = 0; r < 4; r++) {
            cbS[r] = __shfl(cS, 4 * g + r);
            cbP[r] = __shfl(cP, 4 * g + r);
            lb[r]  = __shfl(rl, 4 * g + r);
        }
        #pragma unroll
        for (int nc = 0; nc < 4; nc++) {
            f32x4 oP = *(const f32x4*)&Osh[pw][nc][lane][0];
            #pragma unroll
            for (int r = 0; r < 4; r++) {
                const int trow = t0 + wave * 16 + 4 * g + r;
                float val = (oS[nc][r] * cbS[r] + oP[r] * cbP[r]) * lb[r];
                ctx[(size_t)(b * Tn + trow) * 1024 + h * 64 + nc * 16 + c] = f2bf(val);
            }
        }
        __syncthreads();
    }
}

// ---------------- launch ----------------
extern "C" void kernel_launch(void* const* d_in, const int* in_sizes, int n_in,
                              void* d_out, int out_size, void* d_ws, size_t ws_size,
                              hipStream_t stream) {
    const float* x   = (const float*)d_in[0];
    const float* Wq  = (const float*)d_in[1];
    const float* Wk  = (const float*)d_in[2];
    const float* Wv  = (const float*)d_in[3];
    const float* Wo  = (const float*)d_in[4];
    const float* bo  = (const float*)d_in[5];
    const float* W1  = (const float*)d_in[6];
    const float* b1  = (const float*)d_in[7];
    const float* W2  = (const float*)d_in[8];
    const float* b2  = (const float*)d_in[9];
    const float* g1  = (const float*)d_in[10];
    const float* be1 = (const float*)d_in[11];
    const float* g2  = (const float*)d_in[12];
    const float* be2 = (const float*)d_in[13];

    char* ws = (char*)d_ws;
    unsigned short* wqkv = (unsigned short*)ws;  ws += (size_t)3072 * 1024 * 2;
    unsigned short* wo   = (unsigned short*)ws;  ws += (size_t)1024 * 1024 * 2;
    unsigned short* w1   = (unsigned short*)ws;  ws += (size_t)3072 * 1024 * 2;
    unsigned short* w2   = (unsigned short*)ws;  ws += (size_t)1024 * 3072 * 2;
    unsigned short* bufA = (unsigned short*)ws;  ws += (size_t)Mrows * 1024 * 2; // xn1 / ctx / h2
    unsigned short* bufB = (unsigned short*)ws;  ws += (size_t)Mrows * 3072 * 2; // qkv / ffh

    float* xout = (float*)d_out;           // x1 lives here after out-proj
    unsigned short* vt = (unsigned short*)d_out;   // V^T parks in dead d_out

    // weight prep (single fused launch, 4 elems/thread)
    cast_all_kernel<<<10240, 256, 0, stream>>>(Wq, Wk, Wv, Wo, W1, W2,
                                               wqkv, wo, w1, w2);

    // xn1 = LN(x)
    ln_kernel<<<Mrows, 256, 0, stream>>>(x, g1, be1, bufA);
    // qkv = xn1 @ Wqkv^T  (V third written directly as V^T into vt)
    gemm_bt<0><<<dim3(32, 24), 512, 0, stream>>>(bufA, wqkv, bufB, nullptr, nullptr,
                                                 vt, Mrows, 3072, 1024);
    // ctx = attention(qkv, vt)
    attn_kernel<<<dim3(1024), 128, 0, stream>>>(bufB, vt, bufA);
    // x1 = x + ctx @ Wo^T + bo   (f32, into d_out; vt dead afterwards)
    gemm_bt<1><<<dim3(32, 8), 512, 0, stream>>>(bufA, wo, xout, bo, x,
                                                nullptr, Mrows, 1024, 1024);
    // h2 = LN(x1)
    ln_kernel<<<Mrows, 256, 0, stream>>>(xout, g2, be2, bufA);
    // ffh = relu(h2 @ W1^T + b1)
    gemm_bt<2><<<dim3(32, 24), 512, 0, stream>>>(bufA, w1, bufB, b1, nullptr,
                                                 nullptr, Mrows, 3072, 1024);
    // out = x1 + ffh @ W2^T + b2  (in-place residual from d_out)
    gemm_bt<1><<<dim3(32, 8), 512, 0, stream>>>(bufB, w2, xout, b2, (const float*)xout,
                                                nullptr, Mrows, 1024, 3072);
}